// Round 14
// baseline (405.101 us; speedup 1.0000x reference)
//
#include <hip/hip_runtime.h>
#include <math.h>

// Problem constants
#define BB 8
#define NN 4096      // 64*64 tokens
#define CD 512       // channels
#define HH 8
#define DD 64
#define OC3 1536     // 3*hidden
#define NSPLIT 16

typedef _Float16 f16;
typedef _Float16 half8 __attribute__((ext_vector_type(8)));
typedef _Float16 half4v __attribute__((ext_vector_type(4)));
typedef float f32x4 __attribute__((ext_vector_type(4)));
typedef float f32x16 __attribute__((ext_vector_type(16)));

__device__ __forceinline__ void gload_lds16(const void* g, void* l) {
    __builtin_amdgcn_global_load_lds(
        (const __attribute__((address_space(1))) unsigned int*)g,
        (__attribute__((address_space(3))) unsigned int*)l, 16, 0, 0);
}

// ---------------------------------------------------------------------------
// split w_qkv [1536][512] f32 -> wh, wl [1536][512] f16, scaled by 64
// ---------------------------------------------------------------------------
__global__ __launch_bounds__(256) void split_w_kernel(
    const float* __restrict__ w, f16* __restrict__ wh, f16* __restrict__ wl)
{
    int idx = blockIdx.x * 256 + threadIdx.x;      // OC3*CD/4 = 196608 total
    float4 v = ((const float4*)w)[idx];
    float a[4] = {v.x, v.y, v.z, v.w};
    half4v h, l;
    #pragma unroll
    for (int i = 0; i < 4; ++i) {
        float s = a[i] * 64.f;
        f16 hh = (f16)s;
        h[i] = hh;
        l[i] = (f16)(s - (float)hh);
    }
    *(half4v*)(&wh[(long)idx * 4]) = h;
    *(half4v*)(&wl[(long)idx * 4]) = l;
}

// ---------------------------------------------------------------------------
// split + transpose x [b][512 c][4096 n] f32 -> xth, xtl [b][4096 n][512 c]
// f16, scaled by 16.  64x64 tile, half8 (16B) coalesced writes.
// ---------------------------------------------------------------------------
__global__ __launch_bounds__(256) void split_x_kernel(
    const float* __restrict__ x, f16* __restrict__ xth, f16* __restrict__ xtl)
{
    __shared__ float tile[64][65];
    int b = blockIdx.z;
    int n0 = blockIdx.x * 64, c0 = blockIdx.y * 64;
    const float* xb = x + ((long)b * CD + c0) * NN + n0;
    int t = threadIdx.x;
    int tr = t >> 6, tc = t & 63;
    #pragma unroll
    for (int i = 0; i < 16; ++i)
        tile[tr + i * 4][tc] = xb[(long)(tr + i * 4) * NN + tc];
    __syncthreads();

    int nl = t >> 3, ck = (t & 7) * 8;
    long obase = ((long)b * NN + n0) * CD + c0;
    #pragma unroll
    for (int p = 0; p < 2; ++p) {
        int n = nl + p * 32;
        half8 h, l;
        #pragma unroll
        for (int j = 0; j < 8; ++j) {
            float s = tile[ck + j][n] * 16.f;
            f16 hv = (f16)s;
            h[j] = hv;
            l[j] = (f16)(s - (float)hv);
        }
        *(half8*)(&xth[obase + (long)n * CD + ck]) = h;
        *(half8*)(&xtl[obase + (long)n * CD + ck]) = l;
    }
}

// ---------------------------------------------------------------------------
// qkv GEMM: split-f16 MFMA 32x32x16 (was 16x16x32). K=512, 3 products
// hh+hl+lh, fp32 accum. Block 512 thr = 8 waves (2Mx4N), tile 256x256,
// wave tile 128x64, KT=32, 2-phase dbuf LDS 128 KB, single-phase K-loop
// (R12 structure).  48 MFMA/step/wave vs 96 -> +20% peak FLOP/cyc, half
// the issue slots; identical LDS traffic (24 ds_read_b128/step/wave).
// A frag: row=lane&31, k=(lane>>5)*8+j (analog of verified 16x16 layout).
// C/D: col=lane&31, row=(reg&3)+8*(reg>>2)+4*(lane>>5)  [m74/m101].
//   m0 <  512 : q third -> fused softmax-over-d -> split-f16 (p*32)
//   m0 >= 1024: v third -> split-f16 (x16) into qkv's v region
//   else      : k third -> fp32
// ---------------------------------------------------------------------------
#define AR  16384   // per-operand-array LDS bytes (256 rows x 64B)
#define BUF 65536   // per-dbuf bytes

#define STAGE(Lb, k0s)  do {                                                   \
    long kb_ = (long)(k0s) * 2;                                                \
    _Pragma("unroll")                                                          \
    for (int c_ = 0; c_ < 2; ++c_) {                                           \
        long rowoff_ = (long)(rb0 + c_ * 16) * 1024;                           \
        long ldsoff_ = (long)(rb0 + c_ * 16) * 64;                             \
        gload_lds16(gA_h + rowoff_ + kb_ + g_lane, (Lb) + 0 * AR + ldsoff_);   \
        gload_lds16(gA_l + rowoff_ + kb_ + g_lane, (Lb) + 1 * AR + ldsoff_);   \
        gload_lds16(gB_h + rowoff_ + kb_ + g_lane, (Lb) + 2 * AR + ldsoff_);   \
        gload_lds16(gB_l + rowoff_ + kb_ + g_lane, (Lb) + 3 * AR + ldsoff_);   \
    } } while (0)

__global__ __launch_bounds__(512, 2) void mfma_gemm_kernel(
    const f16* __restrict__ Ah, const f16* __restrict__ Al, long sA,
    const f16* __restrict__ Bh, const f16* __restrict__ Bl, long sB,
    float* __restrict__ Cp, long sC, int ldC, float base_sc)
{
    __shared__ f16 lds[2][4][256 * 32];  // 128 KB
    int bz = blockIdx.z;
    int n0 = blockIdx.x * 256, m0 = blockIdx.y * 256;
    int t = threadIdx.x;
    int lane = t & 63, wid = t >> 6;     // 8 waves
    int wy = wid >> 2, wx = wid & 3;     // 2 (M) x 4 (N)

    int cl = (lane & 3) ^ ((lane >> 3) & 3);
    long g_lane = (long)(lane >> 2) * 1024 + (long)cl * 16;

    const char* gA_h = (const char*)(Ah + bz * sA) + (long)m0 * 1024;
    const char* gA_l = (const char*)(Al + bz * sA) + (long)m0 * 1024;
    const char* gB_h = (const char*)(Bh + bz * sB) + (long)n0 * 1024;
    const char* gB_l = (const char*)(Bl + bz * sB) + (long)n0 * 1024;

    char* L0 = (char*)&lds[0][0][0];
    int rb0 = wid * 32;

    int l31 = lane & 31, l15 = lane & 15, hi5 = lane >> 5;
    int swz = (l15 >> 1) & 3;
    int cpk0 = hi5 ^ swz;              // physical chunk, k 0..15
    int cpk1 = (2 | hi5) ^ swz;        // physical chunk, k 16..31
    long offA = (long)(wy * 128 + l31) * 64;   // + i*2048
    long offB = (long)(wx * 64 + l31) * 64;    // + j*2048

    f32x16 acc[4][2];
    #pragma unroll
    for (int i = 0; i < 4; ++i)
        #pragma unroll
        for (int j = 0; j < 2; ++j)
            #pragma unroll
            for (int r = 0; r < 16; ++r)
                acc[i][j][r] = 0.f;

    STAGE(L0, 0);
    asm volatile("s_waitcnt vmcnt(0)" ::: "memory");
    __syncthreads();

    for (int s = 0; s < 16; ++s) {
        char* Lc = L0 + ((s & 1) ? BUF : 0);
        if (s < 15) {
            char* Ln = L0 + (((s + 1) & 1) ? BUF : 0);
            STAGE(Ln, (s + 1) * 32);
        }

        half8 a0h[4], a0l[4], a1h[4], a1l[4];
        #pragma unroll
        for (int i = 0; i < 4; ++i) {
            a0h[i] = *(const half8*)(Lc + 0 * AR + offA + i * 2048 + cpk0 * 16);
            a0l[i] = *(const half8*)(Lc + 1 * AR + offA + i * 2048 + cpk0 * 16);
            a1h[i] = *(const half8*)(Lc + 0 * AR + offA + i * 2048 + cpk1 * 16);
            a1l[i] = *(const half8*)(Lc + 1 * AR + offA + i * 2048 + cpk1 * 16);
        }
        half8 b0h[2], b0l[2], b1h[2], b1l[2];
        #pragma unroll
        for (int j = 0; j < 2; ++j) {
            b0h[j] = *(const half8*)(Lc + 2 * AR + offB + j * 2048 + cpk0 * 16);
            b0l[j] = *(const half8*)(Lc + 3 * AR + offB + j * 2048 + cpk0 * 16);
            b1h[j] = *(const half8*)(Lc + 2 * AR + offB + j * 2048 + cpk1 * 16);
            b1l[j] = *(const half8*)(Lc + 3 * AR + offB + j * 2048 + cpk1 * 16);
        }
        #pragma unroll
        for (int j = 0; j < 2; ++j)
            #pragma unroll
            for (int i = 0; i < 4; ++i) {
                acc[i][j] = __builtin_amdgcn_mfma_f32_32x32x16_f16(a0h[i], b0h[j], acc[i][j], 0, 0, 0);
                acc[i][j] = __builtin_amdgcn_mfma_f32_32x32x16_f16(a0h[i], b0l[j], acc[i][j], 0, 0, 0);
                acc[i][j] = __builtin_amdgcn_mfma_f32_32x32x16_f16(a0l[i], b0h[j], acc[i][j], 0, 0, 0);
                acc[i][j] = __builtin_amdgcn_mfma_f32_32x32x16_f16(a1h[i], b1h[j], acc[i][j], 0, 0, 0);
                acc[i][j] = __builtin_amdgcn_mfma_f32_32x32x16_f16(a1h[i], b1l[j], acc[i][j], 0, 0, 0);
                acc[i][j] = __builtin_amdgcn_mfma_f32_32x32x16_f16(a1l[i], b1h[j], acc[i][j], 0, 0, 0);
            }

        asm volatile("s_waitcnt vmcnt(0)" ::: "memory");
        __syncthreads();
    }

    // C/D: col = lane&31, row = i*32 + (r&3) + 8*(r>>2) + 4*hi5
    int colb = n0 + wx * 64 + l31;

    if (m0 < 512) {
        // q third: head = (m0>>6) + wy*2 + (i>>1); d = (i&1)*32 + rowpart
        int h0 = (m0 >> 6) + wy * 2;
        f16* qh_b = (f16*)(Cp + (long)bz * sC);
        f16* ql_b = qh_b + (long)CD * NN;
        #pragma unroll
        for (int i = 0; i < 4; ++i)
            #pragma unroll
            for (int j = 0; j < 2; ++j)
                #pragma unroll
                for (int r = 0; r < 16; ++r)
                    acc[i][j][r] *= base_sc;
        #pragma unroll
        for (int j = 0; j < 2; ++j) {
            long nj = colb + j * 32;
            #pragma unroll
            for (int g = 0; g < 2; ++g) {
                float mx = -INFINITY;
                #pragma unroll
                for (int ii = 0; ii < 2; ++ii)
                    #pragma unroll
                    for (int r = 0; r < 16; ++r)
                        mx = fmaxf(mx, acc[2 * g + ii][j][r]);
                mx = fmaxf(mx, __shfl_xor(mx, 32));
                float sum = 0.f;
                #pragma unroll
                for (int ii = 0; ii < 2; ++ii)
                    #pragma unroll
                    for (int r = 0; r < 16; ++r) {
                        float e = expf(acc[2 * g + ii][j][r] - mx);
                        acc[2 * g + ii][j][r] = e;
                        sum += e;
                    }
                sum += __shfl_xor(sum, 32);
                float rj = 32.f / sum;
                long off = nj * CD + (h0 + g) * 64;
                #pragma unroll
                for (int ii = 0; ii < 2; ++ii)
                    #pragma unroll
                    for (int rq = 0; rq < 4; ++rq) {
                        half4v hh, ll;
                        #pragma unroll
                        for (int rr = 0; rr < 4; ++rr) {
                            float v = acc[2 * g + ii][j][rq * 4 + rr] * rj;
                            f16 hv = (f16)v;
                            hh[rr] = hv;
                            ll[rr] = (f16)(v - (float)hv);
                        }
                        int d = ii * 32 + 8 * rq + 4 * hi5;
                        *(half4v*)(qh_b + off + d) = hh;
                        *(half4v*)(ql_b + off + d) = ll;
                    }
            }
        }
        return;
    }

    if (m0 >= 1024) {
        // v third: split-f16 (value = v_true * 16) into qkv's v region
        f16* vhp = (f16*)(Cp + (long)bz * sC + 2L * CD * NN);
        f16* vlp = vhp + (long)CD * NN;
        float vsc = base_sc * 16.f;
        #pragma unroll
        for (int i = 0; i < 4; ++i)
            #pragma unroll
            for (int j = 0; j < 2; ++j)
                #pragma unroll
                for (int r = 0; r < 16; ++r) {
                    long row = m0 + wy * 128 + i * 32 + (r & 3) + 8 * (r >> 2) + 4 * hi5 - 1024;
                    float val = acc[i][j][r] * vsc;
                    f16 hv = (f16)val;
                    vhp[row * NN + colb + j * 32] = hv;
                    vlp[row * NN + colb + j * 32] = (f16)(val - (float)hv);
                }
        return;
    }

    // k third: fp32
    float* outp = Cp + bz * sC;
    #pragma unroll
    for (int i = 0; i < 4; ++i)
        #pragma unroll
        for (int j = 0; j < 2; ++j)
            #pragma unroll
            for (int r = 0; r < 16; ++r) {
                int row = m0 + wy * 128 + i * 32 + (r & 3) + 8 * (r >> 2) + 4 * hi5;
                outp[(long)row * ldC + colb + j * 32] = acc[i][j][r] * base_sc;
            }
}

// ---------------------------------------------------------------------------
// GEMM2: split-f16 MFMA 16x16x32, K=512, 128x128 tile, 4 waves 2x2,
// wave 64x64, 2-phase dbuf, 64 KB LDS. (R7-proven, unchanged.)
// ---------------------------------------------------------------------------
#define AR2  8192
#define BUF2 32768

#define STAGE2(Lb, k0s)  do {                                                  \
    long kb_ = (long)(k0s) * 2;                                                \
    _Pragma("unroll")                                                          \
    for (int c_ = 0; c_ < 2; ++c_) {                                           \
        long rowoff_ = (long)(rb0 + c_ * 16) * 1024;                           \
        long ldsoff_ = (long)(rb0 + c_ * 16) * 64;                             \
        gload_lds16(gA_h + rowoff_ + kb_ + g_lane, (Lb) + 0 * AR2 + ldsoff_);  \
        gload_lds16(gA_l + rowoff_ + kb_ + g_lane, (Lb) + 1 * AR2 + ldsoff_);  \
        gload_lds16(gB_h + rowoff_ + kb_ + g_lane, (Lb) + 2 * AR2 + ldsoff_);  \
        gload_lds16(gB_l + rowoff_ + kb_ + g_lane, (Lb) + 3 * AR2 + ldsoff_);  \
    } } while (0)

__global__ __launch_bounds__(256) void mfma_gemm128_kernel(
    const f16* __restrict__ Ah, const f16* __restrict__ Al, long sA,
    const f16* __restrict__ Bh, const f16* __restrict__ Bl, long sB,
    float* __restrict__ Cp, long sC, int ldC,
    const float* __restrict__ bias, const float* __restrict__ inv_sc,
    float base_sc)
{
    __shared__ f16 lds[2][4][128 * 32];  // 64 KB
    int bz = blockIdx.z;
    int n0 = blockIdx.x * 128, m0 = blockIdx.y * 128;
    int t = threadIdx.x;
    int lane = t & 63, wid = t >> 6;
    int wy = wid >> 1, wx = wid & 1;

    int cl = (lane & 3) ^ ((lane >> 3) & 3);
    long g_lane = (long)(lane >> 2) * 1024 + (long)cl * 16;

    const char* gA_h = (const char*)(Ah + bz * sA) + (long)m0 * 1024;
    const char* gA_l = (const char*)(Al + bz * sA) + (long)m0 * 1024;
    const char* gB_h = (const char*)(Bh + bz * sB) + (long)n0 * 1024;
    const char* gB_l = (const char*)(Bl + bz * sB) + (long)n0 * 1024;

    char* L0 = (char*)&lds[0][0][0];
    int rb0 = wid * 32;

    int cp = (lane >> 4) ^ (((lane & 15) >> 1) & 3);
    long offA = (long)(wy * 64 + (lane & 15)) * 64 + (long)cp * 16;
    long offB = (long)(wx * 64 + (lane & 15)) * 64 + (long)cp * 16;

    f32x4 acc[4][4];
    #pragma unroll
    for (int i = 0; i < 4; ++i)
        #pragma unroll
        for (int j = 0; j < 4; ++j)
            acc[i][j] = (f32x4){0.f, 0.f, 0.f, 0.f};

    STAGE2(L0, 0);
    asm volatile("s_waitcnt vmcnt(0)" ::: "memory");
    __syncthreads();

    for (int s = 0; s < 16; ++s) {
        char* Lc = L0 + ((s & 1) ? BUF2 : 0);
        if (s < 15) {
            char* Ln = L0 + (((s + 1) & 1) ? BUF2 : 0);
            STAGE2(Ln, (s + 1) * 32);
        }

        half8 ah[4], al[4], bh[4], bl[4];
        #pragma unroll
        for (int i = 0; i < 4; ++i) {
            ah[i] = *(const half8*)(Lc + 0 * AR2 + offA + i * 1024);
            al[i] = *(const half8*)(Lc + 1 * AR2 + offA + i * 1024);
            bh[i] = *(const half8*)(Lc + 2 * AR2 + offB + i * 1024);
            bl[i] = *(const half8*)(Lc + 3 * AR2 + offB + i * 1024);
        }
        #pragma unroll
        for (int i = 0; i < 4; ++i)
            #pragma unroll
            for (int j = 0; j < 4; ++j) {
                acc[i][j] = __builtin_amdgcn_mfma_f32_16x16x32_f16(ah[i], bh[j], acc[i][j], 0, 0, 0);
                acc[i][j] = __builtin_amdgcn_mfma_f32_16x16x32_f16(ah[i], bl[j], acc[i][j], 0, 0, 0);
                acc[i][j] = __builtin_amdgcn_mfma_f32_16x16x32_f16(al[i], bh[j], acc[i][j], 0, 0, 0);
            }

        asm volatile("s_waitcnt vmcnt(0)" ::: "memory");
        __syncthreads();
    }

    int colb = n0 + wx * 64 + (lane & 15);
    int rowb = m0 + wy * 64 + ((lane >> 4) << 2);
    float* outp = Cp + bz * sC;
    float mult = base_sc * (inv_sc ? inv_sc[bz] : 1.f);
    #pragma unroll
    for (int i = 0; i < 4; ++i)
        #pragma unroll
        for (int j = 0; j < 4; ++j)
            #pragma unroll
            for (int r = 0; r < 4; ++r) {
                int row = rowb + i * 16 + r;
                float bb = bias ? bias[row] : 0.f;
                outp[(long)row * ldC + colb + j * 16] = acc[i][j][r] * mult + bb;
            }
}

// ---------------------------------------------------------------------------
// k softmax over tokens (4096 contiguous); emit split-f16 k_s * 4096 into
// d_out: per batch kh [512][4096], kl [512][4096].
// ---------------------------------------------------------------------------
__global__ __launch_bounds__(256) void softmax_k_kernel(
    const float* __restrict__ qkv, f16* __restrict__ ksp)
{
    int row = blockIdx.x;              // b*512 + hd
    int b = row >> 9;
    int hd = row & (CD - 1);
    const float* base = qkv + ((long)b * OC3 + CD + hd) * NN;
    f16* khb = ksp + (long)b * 2 * CD * NN + (long)hd * NN;
    f16* klb = khb + (long)CD * NN;
    int t = threadIdx.x;

    float v[16];
    #pragma unroll
    for (int i = 0; i < 16; ++i) v[i] = base[t + i * 256];

    __shared__ float red[256];
    float mx = -INFINITY;
    #pragma unroll
    for (int i = 0; i < 16; ++i) mx = fmaxf(mx, v[i]);
    red[t] = mx; __syncthreads();
    for (int off = 128; off > 0; off >>= 1) {
        if (t < off) red[t] = fmaxf(red[t], red[t + off]);
        __syncthreads();
    }
    mx = red[0]; __syncthreads();

    float s = 0.f;
    #pragma unroll
    for (int i = 0; i < 16; ++i) {
        v[i] = expf(v[i] - mx);
        s += v[i];
    }
    red[t] = s; __syncthreads();
    for (int off = 128; off > 0; off >>= 1) {
        if (t < off) red[t] += red[t + off];
        __syncthreads();
    }
    float inv = 4096.f / red[0];       // k_s scaled by 2^12 for f16 split

    #pragma unroll
    for (int i = 0; i < 16; ++i) {
        float val = v[i] * inv;
        f16 hv = (f16)val;
        khb[t + i * 256] = hv;
        klb[t + i * 256] = (f16)(val - (float)hv);
    }
}

// ---------------------------------------------------------------------------
// context partials via split-f16 MFMA: per (bh, sp) block computes
// acc[64 d][64 e] = sum over 256 n of (k_s*2^12)(v*2^4), 3 products.
// k from d_out (ksp, pre-split), v from qkv's v region (pre-split).
// ---------------------------------------------------------------------------
__global__ __launch_bounds__(256) void ctx_mfma_kernel(
    const f16* __restrict__ ksp, const float* __restrict__ qkv,
    float* __restrict__ ctxp)
{
    __shared__ f16 lds[4][64 * 32];          // kh,kl,vh,vl tiles; 4 KB each
    int sp = blockIdx.x;                     // K-split 0..15
    int bh = blockIdx.y;                     // 0..63
    int b = bh >> 3, h = bh & 7;
    int t = threadIdx.x, lane = t & 63, w = t >> 6;

    const char* khg = (const char*)(ksp + (long)b * 2 * CD * NN) + (long)h * 64 * (NN * 2);
    const char* klg = khg + (long)CD * NN * 2;
    const char* vhg = (const char*)(qkv + ((long)b * OC3 + 2L * CD) * NN) + (long)h * 64 * (NN * 2);
    const char* vlg = vhg + (long)CD * NN * 2;
    const char* gw = (w == 0) ? khg : (w == 1) ? klg : (w == 2) ? vhg : vlg;

    int cl = (lane & 3) ^ ((lane >> 3) & 3);
    char* larr = (char*)&lds[0][0] + w * 4096;
    char* L = (char*)&lds[0][0];
    int cp16 = ((lane >> 4) ^ (((lane & 15) >> 1) & 3)) * 16;
    int lr = lane & 15;

    f32x4 acc[4];
    #pragma unroll
    for (int i = 0; i < 4; ++i) acc[i] = (f32x4){0.f, 0.f, 0.f, 0.f};

    for (int ks = 0; ks < 8; ++ks) {
        long kbyte = ((long)sp * 256 + ks * 32) * 2;
        #pragma unroll
        for (int c = 0; c < 4; ++c)
            gload_lds16(gw + (long)(c * 16 + (lane >> 2)) * (NN * 2) + kbyte + (long)cl * 16,
                        larr + c * 1024 + lane * 16);
        asm volatile("s_waitcnt vmcnt(0)" ::: "memory");
        __syncthreads();

        half8 ah[4], al[4], bhf, blf;
        #pragma unroll
        for (int i = 0; i < 4; ++i) {
            ah[i] = *(const half8*)(L + 0 * 4096 + (i * 16 + lr) * 64 + cp16);
            al[i] = *(const half8*)(L + 1 * 4096 + (i * 16 + lr) * 64 + cp16);
        }
        bhf = *(const half8*)(L + 2 * 4096 + (w * 16 + lr) * 64 + cp16);
        blf = *(const half8*)(L + 3 * 4096 + (w * 16 + lr) * 64 + cp16);
        #pragma unroll
        for (int i = 0; i < 4; ++i) {
            acc[i] = __builtin_amdgcn_mfma_f32_16x16x32_f16(ah[i], bhf, acc[i], 0, 0, 0);
            acc[i] = __builtin_amdgcn_mfma_f32_16x16x32_f16(ah[i], blf, acc[i], 0, 0, 0);
            acc[i] = __builtin_amdgcn_mfma_f32_16x16x32_f16(al[i], bhf, acc[i], 0, 0, 0);
        }
        __syncthreads();
    }

    float* op = ctxp + ((long)bh * NSPLIT + sp) * 4096;
    #pragma unroll
    for (int i = 0; i < 4; ++i)
        #pragma unroll
        for (int r = 0; r < 4; ++r)
            op[(i * 16 + (lane >> 4) * 4 + r) * 64 + w * 16 + lr] = acc[i][r];
}

// ---------------------------------------------------------------------------
// reduce partials in fp64; undo scales: /(2^12 * 2^4) and /N  => * 2^-28
// ---------------------------------------------------------------------------
__global__ __launch_bounds__(256) void context_reduce_kernel(
    const float* __restrict__ ctxp, float* __restrict__ ctx)
{
    int idx = blockIdx.x * 256 + threadIdx.x;
    int bh = idx >> 12;
    int de = idx & 4095;
    double s = 0.0;
    #pragma unroll
    for (int sp = 0; sp < NSPLIT; ++sp)
        s += (double)ctxp[((long)bh * NSPLIT + sp) * 4096 + de];
    ctx[idx] = (float)(s * (1.0 / 268435456.0));
}

// ---------------------------------------------------------------------------
// fold w_out into per-batch M (row-major [c][hd]) — LDS-tiled:
// block = (c-tile 128, bh); ctx[b,h] (64x64) staged once in LDS (65-pad).
// ---------------------------------------------------------------------------
__global__ __launch_bounds__(256) void fold_wout_kernel(
    const float* __restrict__ w_out, const float* __restrict__ ctx,
    float* __restrict__ Mf)
{
    __shared__ float cl[64][65];
    int ct = blockIdx.x;               // c-tile 0..3
    int bh = blockIdx.y;               // b*8+h
    int b = bh >> 3, h = bh & 7;
    int t = threadIdx.x;
    const float* cp = ctx + (long)bh * 4096;
    #pragma unroll
    for (int i = 0; i < 16; ++i) {
        int o = t + i * 256;
        cl[o >> 6][o & 63] = cp[o];
    }
    __syncthreads();

    int d = t & 63, tc = t >> 6;       // 4 c-subgroups of 32
    #pragma unroll 4
    for (int ci = 0; ci < 32; ++ci) {
        int c = ct * 128 + tc * 32 + ci;
        const float* wr = w_out + (long)c * CD + h * DD;
        float s = 0.f;
        #pragma unroll
        for (int e = 0; e < 64; ++e) s += wr[e] * cl[d][e];
        Mf[((long)b * CD + c) * CD + h * DD + d] = s;
    }
}

// ---------------------------------------------------------------------------
// per-batch max|M| two-stage: 32 partial blocks per batch, then final.
// ---------------------------------------------------------------------------
__global__ __launch_bounds__(256) void max_m_part_kernel(
    const float* __restrict__ Mf, float* __restrict__ part)
{
    int blk = blockIdx.x;              // 256 blocks: b = blk>>5, sub = blk&31
    int b = blk >> 5, sub = blk & 31;
    const float4* p = (const float4*)(Mf + (long)b * CD * CD) + (long)sub * 2048;
    float mx = 0.f;
    for (int i = threadIdx.x; i < 2048; i += 256) {
        float4 v = p[i];
        mx = fmaxf(mx, fmaxf(fmaxf(fabsf(v.x), fabsf(v.y)),
                             fmaxf(fabsf(v.z), fabsf(v.w))));
    }
    __shared__ float red[256];
    red[threadIdx.x] = mx; __syncthreads();
    for (int off = 128; off > 0; off >>= 1) {
        if (threadIdx.x < off) red[threadIdx.x] = fmaxf(red[threadIdx.x], red[threadIdx.x + off]);
        __syncthreads();
    }
    if (threadIdx.x == 0) part[blk] = red[0];
}

__global__ __launch_bounds__(64) void max_m_final_kernel(
    const float* __restrict__ part, float* __restrict__ scl)
{
    int b = threadIdx.x;
    if (b < 8) {
        float m = 0.f;
        #pragma unroll
        for (int i = 0; i < 32; ++i) m = fmaxf(m, part[b * 32 + i]);
        int e = (m > 1e-30f) ? ilogbf(m) : 0;
        scl[b] = ldexpf(1.f, 10 - e);
        scl[8 + b] = ldexpf(1.f, e - 10);
    }
}

// ---------------------------------------------------------------------------
// split M fp32 -> mh/ml f16 with per-batch scale
// ---------------------------------------------------------------------------
__global__ __launch_bounds__(256) void split_m_kernel(
    const float* __restrict__ Mf, const float* __restrict__ scl,
    f16* __restrict__ mh, f16* __restrict__ ml)
{
    int idx = blockIdx.x * 256 + threadIdx.x;   // BB*CD*CD/4 float4s
    float s = scl[idx >> 16];                   // 65536 float4s per batch
    float4 v = ((const float4*)Mf)[idx];
    float a[4] = {v.x, v.y, v.z, v.w};
    half4v h, l;
    #pragma unroll
    for (int i = 0; i < 4; ++i) {
        float tval = a[i] * s;
        f16 hv = (f16)tval;
        h[i] = hv;
        l[i] = (f16)(tval - (float)hv);
    }
    *(half4v*)(&mh[(long)idx * 4]) = h;
    *(half4v*)(&ml[(long)idx * 4]) = l;
}

// ---------------------------------------------------------------------------
// channel LayerNorm over c=512 (stride NN), fp64 stats, values reg-cached.
// ---------------------------------------------------------------------------
__global__ __launch_bounds__(256) void layernorm_kernel(
    const float* __restrict__ qkv, const float* __restrict__ g,
    float* __restrict__ out)
{
    int t = threadIdx.x;
    int tn = t & 31, cy = t >> 5;              // col-in-block, c-group
    long col = (long)blockIdx.x * 32 + tn;     // 0..32767
    int n = (int)(col & (NN - 1));
    int b = (int)(col >> 12);
    const float* base = qkv + (long)b * OC3 * NN + (long)CD * NN + n;

    float v[64];
    double s = 0.0, ss = 0.0;
    #pragma unroll
    for (int i = 0; i < 64; ++i) {
        v[i] = base[(long)(cy * 64 + i) * NN];
        s += (double)v[i];
        ss += (double)v[i] * (double)v[i];
    }

    __shared__ double rs[8][32], rss[8][32];
    rs[cy][tn] = s; rss[cy][tn] = ss;
    __syncthreads();
    __shared__ float mb[32], ib[32];
    if (cy == 0) {
        double S = 0.0, SS = 0.0;
        #pragma unroll
        for (int j = 0; j < 8; ++j) { S += rs[j][tn]; SS += rss[j][tn]; }
        double mean = S * (1.0 / CD);
        double var = SS * (1.0 / CD) - mean * mean;
        mb[tn] = (float)mean;
        ib[tn] = (float)(1.0 / sqrt(var + 1e-5));
    }
    __syncthreads();
    float m = mb[tn], iv = ib[tn];

    float* oc = out + (long)b * CD * NN + n;
    #pragma unroll
    for (int i = 0; i < 64; ++i)
        oc[(long)(cy * 64 + i) * NN] = (v[i] - m) * iv * g[cy * 64 + i];
}

// ---------------------------------------------------------------------------
extern "C" void kernel_launch(void* const* d_in, const int* in_sizes, int n_in,
                              void* d_out, int out_size, void* d_ws, size_t ws_size,
                              hipStream_t stream)
{
    const float* x     = (const float*)d_in[0];
    const float* w_qkv = (const float*)d_in[1];
    const float* w_out = (const float*)d_in[2];
    const float* b_out = (const float*)d_in[3];
    const float* g     = (const float*)d_in[4];
    float* out = (float*)d_out;

    float* ws   = (float*)d_ws;
    float* qkv  = ws;                                      // 50,331,648 f
    float* ctxp = qkv + (long)BB * OC3 * NN;               //  4,194,304 f (reused for Mf)
    float* ctx  = ctxp + (long)BB * HH * NSPLIT * DD * DD; //    262,144 f
    f16*   mh   = (f16*)(ctx + (long)BB * HH * DD * DD);   //  2,097,152 h
    f16*   ml   = mh + (long)BB * CD * CD;                 //  2,097,152 h
    f16*   wh   = (f16*)(ml + (long)BB * CD * CD);         //    786,432 h
    f16*   wl   = wh + (long)OC3 * CD;                     //    786,432 h
    float* scl  = (float*)(wl + (long)OC3 * CD);           //         16 f
    float* part = scl + 16;                                //        256 f
    float* Mf   = ctxp;                                    // ctxp dead by then

    // d_out as scratch, phase-ordered: xth/xtl -> ksp (kh/kl) -> final out
    f16* xth = (f16*)d_out;
    f16* xtl = xth + (long)BB * NN * CD;
    f16* ksp = (f16*)d_out;          // after xth/xtl consumed by qkv GEMM

    // 0) operand splits
    split_w_kernel<<<(OC3 * CD / 4) / 256, 256, 0, stream>>>(w_qkv, wh, wl);
    split_x_kernel<<<dim3(NN / 64, CD / 64, BB), 256, 0, stream>>>(x, xth, xtl);

    // 1) qkv = w_qkv @ x via split-f16 MFMA 32x32x16 (ONLY change vs R12).
    mfma_gemm_kernel<<<dim3(NN / 256, OC3 / 256, BB), 512, 0, stream>>>(
        wh, wl, 0L, xth, xtl, (long)NN * CD,
        qkv, (long)OC3 * NN, NN, 1.0f / 1024.0f);

    // 2) k softmax -> split-f16 k_s (x4096) into d_out
    softmax_k_kernel<<<BB * CD, 256, 0, stream>>>(qkv, ksp);

    // 3) context partials via MFMA (pre-split k and v) + fp64 reduce
    ctx_mfma_kernel<<<dim3(NSPLIT, BB * HH), 256, 0, stream>>>(ksp, qkv, ctxp);
    context_reduce_kernel<<<(BB * HH * DD * DD) / 256, 256, 0, stream>>>(ctxp, ctx);

    // 4) M = fold(w_out, ctx) -> Mf (ws); pow2 scale; f16 split
    fold_wout_kernel<<<dim3(4, BB * HH), 256, 0, stream>>>(w_out, ctx, Mf);
    max_m_part_kernel<<<256, 256, 0, stream>>>(Mf, part);
    max_m_final_kernel<<<1, 64, 0, stream>>>(part, scl);
    split_m_kernel<<<(BB * CD * CD / 4) / 256, 256, 0, stream>>>(Mf, scl, mh, ml);

    // 5) y = M_b @ q_s + b_out via split-f16 MFMA (128x128 tiles) -> dead k
    //    region of qkv.  B operand = qh/ql in q region ([n][512] layout).
    mfma_gemm128_kernel<<<dim3(NN / 128, CD / 128, BB), 256, 0, stream>>>(
        mh, ml, (long)CD * CD,
        (const f16*)qkv, (const f16*)qkv + (long)CD * NN, (long)OC3 * NN * 2,
        qkv + (long)CD * NN, (long)OC3 * NN, NN, b_out, scl + 8, 1.0f / 256.0f);

    // 6) channel LayerNorm -> d_out (overwrites ksp scratch)
    layernorm_kernel<<<(BB * NN) / 32, 256, 0, stream>>>(qkv, g, out);
}

// Round 15
// 381.377 us; speedup vs baseline: 1.0622x; 1.0622x over previous
//
#include <hip/hip_runtime.h>
#include <math.h>

// Problem constants
#define BB 8
#define NN 4096      // 64*64 tokens
#define CD 512       // channels
#define HH 8
#define DD 64
#define OC3 1536     // 3*hidden
#define NSPLIT 16

typedef _Float16 f16;
typedef _Float16 half8 __attribute__((ext_vector_type(8)));
typedef _Float16 half4v __attribute__((ext_vector_type(4)));
typedef float f32x4 __attribute__((ext_vector_type(4)));

__device__ __forceinline__ void gload_lds16(const void* g, void* l) {
    __builtin_amdgcn_global_load_lds(
        (const __attribute__((address_space(1))) unsigned int*)g,
        (__attribute__((address_space(3))) unsigned int*)l, 16, 0, 0);
}

// ---------------------------------------------------------------------------
// split w_qkv [1536][512] f32 -> wh, wl [1536][512] f16, scaled by 64
// ---------------------------------------------------------------------------
__global__ __launch_bounds__(256) void split_w_kernel(
    const float* __restrict__ w, f16* __restrict__ wh, f16* __restrict__ wl)
{
    int idx = blockIdx.x * 256 + threadIdx.x;      // OC3*CD/4 = 196608 total
    float4 v = ((const float4*)w)[idx];
    float a[4] = {v.x, v.y, v.z, v.w};
    half4v h, l;
    #pragma unroll
    for (int i = 0; i < 4; ++i) {
        float s = a[i] * 64.f;
        f16 hh = (f16)s;
        h[i] = hh;
        l[i] = (f16)(s - (float)hh);
    }
    *(half4v*)(&wh[(long)idx * 4]) = h;
    *(half4v*)(&wl[(long)idx * 4]) = l;
}

// ---------------------------------------------------------------------------
// split + transpose x [b][512 c][4096 n] f32 -> xth, xtl [b][4096 n][512 c]
// f16, scaled by 16.  64x64 tile, half8 (16B) coalesced writes.
// ---------------------------------------------------------------------------
__global__ __launch_bounds__(256) void split_x_kernel(
    const float* __restrict__ x, f16* __restrict__ xth, f16* __restrict__ xtl)
{
    __shared__ float tile[64][65];
    int b = blockIdx.z;
    int n0 = blockIdx.x * 64, c0 = blockIdx.y * 64;
    const float* xb = x + ((long)b * CD + c0) * NN + n0;
    int t = threadIdx.x;
    int tr = t >> 6, tc = t & 63;
    #pragma unroll
    for (int i = 0; i < 16; ++i)
        tile[tr + i * 4][tc] = xb[(long)(tr + i * 4) * NN + tc];
    __syncthreads();

    int nl = t >> 3, ck = (t & 7) * 8;
    long obase = ((long)b * NN + n0) * CD + c0;
    #pragma unroll
    for (int p = 0; p < 2; ++p) {
        int n = nl + p * 32;
        half8 h, l;
        #pragma unroll
        for (int j = 0; j < 8; ++j) {
            float s = tile[ck + j][n] * 16.f;
            f16 hv = (f16)s;
            h[j] = hv;
            l[j] = (f16)(s - (float)hv);
        }
        *(half8*)(&xth[obase + (long)n * CD + ck]) = h;
        *(half8*)(&xtl[obase + (long)n * CD + ck]) = l;
    }
}

// ---------------------------------------------------------------------------
// qkv GEMM: split-f16 MFMA, K=512. 3 products hh+hl+lh, fp32 accum.
// Block 512 thr = 8 waves (2Mx4N), tile 256x256, wave tile 128x64, KT=32,
// 2-phase dbuf, LDS 128 KB.  (R12-verified best: 153 us, MfmaUtil 46%.)
//   m0 <  512 : q third -> fused softmax-over-d -> split-f16 (p*32) into
//               q region of qkv, [n][512] layout
//   m0 >= 1024: v third -> split-f16 (x16) into qkv's v region
//   else      : k third -> fp32
// ---------------------------------------------------------------------------
#define AR  16384   // per-operand-array LDS bytes (256 rows x 64B)
#define BUF 65536   // per-dbuf bytes

#define STAGE(Lb, k0s)  do {                                                   \
    long kb_ = (long)(k0s) * 2;                                                \
    _Pragma("unroll")                                                          \
    for (int c_ = 0; c_ < 2; ++c_) {                                           \
        long rowoff_ = (long)(rb0 + c_ * 16) * 1024;                           \
        long ldsoff_ = (long)(rb0 + c_ * 16) * 64;                             \
        gload_lds16(gA_h + rowoff_ + kb_ + g_lane, (Lb) + 0 * AR + ldsoff_);   \
        gload_lds16(gA_l + rowoff_ + kb_ + g_lane, (Lb) + 1 * AR + ldsoff_);   \
        gload_lds16(gB_h + rowoff_ + kb_ + g_lane, (Lb) + 2 * AR + ldsoff_);   \
        gload_lds16(gB_l + rowoff_ + kb_ + g_lane, (Lb) + 3 * AR + ldsoff_);   \
    } } while (0)

__global__ __launch_bounds__(512, 2) void mfma_gemm_kernel(
    const f16* __restrict__ Ah, const f16* __restrict__ Al, long sA,
    const f16* __restrict__ Bh, const f16* __restrict__ Bl, long sB,
    float* __restrict__ Cp, long sC, int ldC, float base_sc)
{
    __shared__ f16 lds[2][4][256 * 32];  // 128 KB
    int bz = blockIdx.z;
    int n0 = blockIdx.x * 256, m0 = blockIdx.y * 256;
    int t = threadIdx.x;
    int lane = t & 63, wid = t >> 6;     // 8 waves
    int wy = wid >> 2, wx = wid & 3;     // 2 (M) x 4 (N)

    int cl = (lane & 3) ^ ((lane >> 3) & 3);
    long g_lane = (long)(lane >> 2) * 1024 + (long)cl * 16;

    const char* gA_h = (const char*)(Ah + bz * sA) + (long)m0 * 1024;
    const char* gA_l = (const char*)(Al + bz * sA) + (long)m0 * 1024;
    const char* gB_h = (const char*)(Bh + bz * sB) + (long)n0 * 1024;
    const char* gB_l = (const char*)(Bl + bz * sB) + (long)n0 * 1024;

    char* L0 = (char*)&lds[0][0][0];
    int rb0 = wid * 32;

    int cp = (lane >> 4) ^ (((lane & 15) >> 1) & 3);
    long offA = (long)(wy * 128 + (lane & 15)) * 64 + (long)cp * 16;
    long offB = (long)(wx * 64 + (lane & 15)) * 64 + (long)cp * 16;

    f32x4 acc[8][4];
    #pragma unroll
    for (int i = 0; i < 8; ++i)
        #pragma unroll
        for (int j = 0; j < 4; ++j)
            acc[i][j] = (f32x4){0.f, 0.f, 0.f, 0.f};

    STAGE(L0, 0);
    asm volatile("s_waitcnt vmcnt(0)" ::: "memory");
    __syncthreads();

    for (int s = 0; s < 16; ++s) {
        char* Lc = L0 + ((s & 1) ? BUF : 0);
        if (s < 15) {
            char* Ln = L0 + (((s + 1) & 1) ? BUF : 0);
            STAGE(Ln, (s + 1) * 32);
        }

        half8 ah[8], al[8];
        #pragma unroll
        for (int i = 0; i < 8; ++i) {
            ah[i] = *(const half8*)(Lc + 0 * AR + offA + i * 1024);
            al[i] = *(const half8*)(Lc + 1 * AR + offA + i * 1024);
        }
        #pragma unroll
        for (int j = 0; j < 4; ++j) {
            half8 bh = *(const half8*)(Lc + 2 * AR + offB + j * 1024);
            half8 bl = *(const half8*)(Lc + 3 * AR + offB + j * 1024);
            #pragma unroll
            for (int i = 0; i < 8; ++i) {
                acc[i][j] = __builtin_amdgcn_mfma_f32_16x16x32_f16(ah[i], bh, acc[i][j], 0, 0, 0);
                acc[i][j] = __builtin_amdgcn_mfma_f32_16x16x32_f16(ah[i], bl, acc[i][j], 0, 0, 0);
                acc[i][j] = __builtin_amdgcn_mfma_f32_16x16x32_f16(al[i], bh, acc[i][j], 0, 0, 0);
            }
        }

        asm volatile("s_waitcnt vmcnt(0)" ::: "memory");
        __syncthreads();
    }

    // C/D layout: col = lane&15, row = (lane>>4)*4 + reg
    int colb = n0 + wx * 64 + (lane & 15);
    int rowb = m0 + wy * 128 + ((lane >> 4) << 2);

    if (m0 < 512) {
        // q third: wave's 128 rows = heads h0, h0+1. Fused softmax over d +
        // split-f16 (p*32 = q_s*256), [n][512] layout.
        int h0 = (m0 >> 6) + wy * 2;
        f16* qh_b = (f16*)(Cp + (long)bz * sC);
        f16* ql_b = qh_b + (long)CD * NN;
        #pragma unroll
        for (int i = 0; i < 8; ++i)
            #pragma unroll
            for (int j = 0; j < 4; ++j)
                #pragma unroll
                for (int r = 0; r < 4; ++r)
                    acc[i][j][r] *= base_sc;
        #pragma unroll
        for (int j = 0; j < 4; ++j) {
            long nj = colb + j * 16;
            #pragma unroll
            for (int g = 0; g < 2; ++g) {
                float mx = -INFINITY;
                #pragma unroll
                for (int di = 0; di < 4; ++di)
                    #pragma unroll
                    for (int r = 0; r < 4; ++r)
                        mx = fmaxf(mx, acc[g * 4 + di][j][r]);
                mx = fmaxf(mx, __shfl_xor(mx, 16));
                mx = fmaxf(mx, __shfl_xor(mx, 32));
                float sum = 0.f;
                #pragma unroll
                for (int di = 0; di < 4; ++di)
                    #pragma unroll
                    for (int r = 0; r < 4; ++r) {
                        float e = expf(acc[g * 4 + di][j][r] - mx);
                        acc[g * 4 + di][j][r] = e;
                        sum += e;
                    }
                sum += __shfl_xor(sum, 16);
                sum += __shfl_xor(sum, 32);
                float rj = 32.f / sum;
                long off = nj * CD + (h0 + g) * 64 + ((lane >> 4) << 2);
                #pragma unroll
                for (int di = 0; di < 4; ++di) {
                    half4v hh, ll;
                    #pragma unroll
                    for (int r = 0; r < 4; ++r) {
                        float v = acc[g * 4 + di][j][r] * rj;
                        f16 hv = (f16)v;
                        hh[r] = hv;
                        ll[r] = (f16)(v - (float)hv);
                    }
                    *(half4v*)(qh_b + off + di * 16) = hh;
                    *(half4v*)(ql_b + off + di * 16) = ll;
                }
            }
        }
        return;
    }

    if (m0 >= 1024) {
        // v third: emit split-f16 (value = v_true * 16) into qkv's v region
        f16* vhp = (f16*)(Cp + (long)bz * sC + 2L * CD * NN);
        f16* vlp = vhp + (long)CD * NN;
        float vsc = base_sc * 16.f;
        #pragma unroll
        for (int i = 0; i < 8; ++i)
            #pragma unroll
            for (int j = 0; j < 4; ++j)
                #pragma unroll
                for (int r = 0; r < 4; ++r) {
                    long row = rowb + i * 16 + r - 1024;
                    float val = acc[i][j][r] * vsc;
                    f16 hv = (f16)val;
                    vhp[row * NN + colb + j * 16] = hv;
                    vlp[row * NN + colb + j * 16] = (f16)(val - (float)hv);
                }
        return;
    }

    // k third: fp32
    float* outp = Cp + bz * sC;
    #pragma unroll
    for (int i = 0; i < 8; ++i)
        #pragma unroll
        for (int j = 0; j < 4; ++j)
            #pragma unroll
            for (int r = 0; r < 4; ++r) {
                int row = rowb + i * 16 + r;
                outp[(long)row * ldC + colb + j * 16] = acc[i][j][r] * base_sc;
            }
}

// ---------------------------------------------------------------------------
// GEMM2: split-f16 MFMA, K=512, 128x128 tile, 4 waves 2x2, wave 64x64,
// 2-phase dbuf, 64 KB LDS (2 blocks/CU).  C = acc*base_sc*inv_sc[bz] + bias.
// ---------------------------------------------------------------------------
#define AR2  8192
#define BUF2 32768

#define STAGE2(Lb, k0s)  do {                                                  \
    long kb_ = (long)(k0s) * 2;                                                \
    _Pragma("unroll")                                                          \
    for (int c_ = 0; c_ < 2; ++c_) {                                           \
        long rowoff_ = (long)(rb0 + c_ * 16) * 1024;                           \
        long ldsoff_ = (long)(rb0 + c_ * 16) * 64;                             \
        gload_lds16(gA_h + rowoff_ + kb_ + g_lane, (Lb) + 0 * AR2 + ldsoff_);  \
        gload_lds16(gA_l + rowoff_ + kb_ + g_lane, (Lb) + 1 * AR2 + ldsoff_);  \
        gload_lds16(gB_h + rowoff_ + kb_ + g_lane, (Lb) + 2 * AR2 + ldsoff_);  \
        gload_lds16(gB_l + rowoff_ + kb_ + g_lane, (Lb) + 3 * AR2 + ldsoff_);  \
    } } while (0)

__global__ __launch_bounds__(256) void mfma_gemm128_kernel(
    const f16* __restrict__ Ah, const f16* __restrict__ Al, long sA,
    const f16* __restrict__ Bh, const f16* __restrict__ Bl, long sB,
    float* __restrict__ Cp, long sC, int ldC,
    const float* __restrict__ bias, const float* __restrict__ inv_sc,
    float base_sc)
{
    __shared__ f16 lds[2][4][128 * 32];  // 64 KB
    int bz = blockIdx.z;
    int n0 = blockIdx.x * 128, m0 = blockIdx.y * 128;
    int t = threadIdx.x;
    int lane = t & 63, wid = t >> 6;
    int wy = wid >> 1, wx = wid & 1;

    int cl = (lane & 3) ^ ((lane >> 3) & 3);
    long g_lane = (long)(lane >> 2) * 1024 + (long)cl * 16;

    const char* gA_h = (const char*)(Ah + bz * sA) + (long)m0 * 1024;
    const char* gA_l = (const char*)(Al + bz * sA) + (long)m0 * 1024;
    const char* gB_h = (const char*)(Bh + bz * sB) + (long)n0 * 1024;
    const char* gB_l = (const char*)(Bl + bz * sB) + (long)n0 * 1024;

    char* L0 = (char*)&lds[0][0][0];
    int rb0 = wid * 32;

    int cp = (lane >> 4) ^ (((lane & 15) >> 1) & 3);
    long offA = (long)(wy * 64 + (lane & 15)) * 64 + (long)cp * 16;
    long offB = (long)(wx * 64 + (lane & 15)) * 64 + (long)cp * 16;

    f32x4 acc[4][4];
    #pragma unroll
    for (int i = 0; i < 4; ++i)
        #pragma unroll
        for (int j = 0; j < 4; ++j)
            acc[i][j] = (f32x4){0.f, 0.f, 0.f, 0.f};

    STAGE2(L0, 0);
    asm volatile("s_waitcnt vmcnt(0)" ::: "memory");
    __syncthreads();

    for (int s = 0; s < 16; ++s) {
        char* Lc = L0 + ((s & 1) ? BUF2 : 0);
        if (s < 15) {
            char* Ln = L0 + (((s + 1) & 1) ? BUF2 : 0);
            STAGE2(Ln, (s + 1) * 32);
        }

        half8 ah[4], al[4], bh[4], bl[4];
        #pragma unroll
        for (int i = 0; i < 4; ++i) {
            ah[i] = *(const half8*)(Lc + 0 * AR2 + offA + i * 1024);
            al[i] = *(const half8*)(Lc + 1 * AR2 + offA + i * 1024);
            bh[i] = *(const half8*)(Lc + 2 * AR2 + offB + i * 1024);
            bl[i] = *(const half8*)(Lc + 3 * AR2 + offB + i * 1024);
        }
        #pragma unroll
        for (int i = 0; i < 4; ++i)
            #pragma unroll
            for (int j = 0; j < 4; ++j) {
                acc[i][j] = __builtin_amdgcn_mfma_f32_16x16x32_f16(ah[i], bh[j], acc[i][j], 0, 0, 0);
                acc[i][j] = __builtin_amdgcn_mfma_f32_16x16x32_f16(ah[i], bl[j], acc[i][j], 0, 0, 0);
                acc[i][j] = __builtin_amdgcn_mfma_f32_16x16x32_f16(al[i], bh[j], acc[i][j], 0, 0, 0);
            }

        asm volatile("s_waitcnt vmcnt(0)" ::: "memory");
        __syncthreads();
    }

    int colb = n0 + wx * 64 + (lane & 15);
    int rowb = m0 + wy * 64 + ((lane >> 4) << 2);
    float* outp = Cp + bz * sC;
    float mult = base_sc * (inv_sc ? inv_sc[bz] : 1.f);
    #pragma unroll
    for (int i = 0; i < 4; ++i)
        #pragma unroll
        for (int j = 0; j < 4; ++j)
            #pragma unroll
            for (int r = 0; r < 4; ++r) {
                int row = rowb + i * 16 + r;
                float bb = bias ? bias[row] : 0.f;
                outp[(long)row * ldC + colb + j * 16] = acc[i][j][r] * mult + bb;
            }
}

// ---------------------------------------------------------------------------
// k softmax over tokens (4096 contiguous); emit split-f16 k_s * 4096 into
// d_out: per batch kh [512][4096], kl [512][4096].
// ---------------------------------------------------------------------------
__global__ __launch_bounds__(256) void softmax_k_kernel(
    const float* __restrict__ qkv, f16* __restrict__ ksp)
{
    int row = blockIdx.x;              // b*512 + hd
    int b = row >> 9;
    int hd = row & (CD - 1);
    const float* base = qkv + ((long)b * OC3 + CD + hd) * NN;
    f16* khb = ksp + (long)b * 2 * CD * NN + (long)hd * NN;
    f16* klb = khb + (long)CD * NN;
    int t = threadIdx.x;

    float v[16];
    #pragma unroll
    for (int i = 0; i < 16; ++i) v[i] = base[t + i * 256];

    __shared__ float red[256];
    float mx = -INFINITY;
    #pragma unroll
    for (int i = 0; i < 16; ++i) mx = fmaxf(mx, v[i]);
    red[t] = mx; __syncthreads();
    for (int off = 128; off > 0; off >>= 1) {
        if (t < off) red[t] = fmaxf(red[t], red[t + off]);
        __syncthreads();
    }
    mx = red[0]; __syncthreads();

    float s = 0.f;
    #pragma unroll
    for (int i = 0; i < 16; ++i) {
        v[i] = expf(v[i] - mx);
        s += v[i];
    }
    red[t] = s; __syncthreads();
    for (int off = 128; off > 0; off >>= 1) {
        if (t < off) red[t] += red[t + off];
        __syncthreads();
    }
    float inv = 4096.f / red[0];       // k_s scaled by 2^12 for f16 split

    #pragma unroll
    for (int i = 0; i < 16; ++i) {
        float val = v[i] * inv;
        f16 hv = (f16)val;
        khb[t + i * 256] = hv;
        klb[t + i * 256] = (f16)(val - (float)hv);
    }
}

// ---------------------------------------------------------------------------
// context partials via split-f16 MFMA: per (bh, sp) block computes
// acc[64 d][64 e] = sum over 256 n of (k_s*2^12)(v*2^4), 3 products.
// k from d_out (ksp, pre-split), v from qkv's v region (pre-split).
// ---------------------------------------------------------------------------
__global__ __launch_bounds__(256) void ctx_mfma_kernel(
    const f16* __restrict__ ksp, const float* __restrict__ qkv,
    float* __restrict__ ctxp)
{
    __shared__ f16 lds[4][64 * 32];          // kh,kl,vh,vl tiles; 4 KB each
    int sp = blockIdx.x;                     // K-split 0..15
    int bh = blockIdx.y;                     // 0..63
    int b = bh >> 3, h = bh & 7;
    int t = threadIdx.x, lane = t & 63, w = t >> 6;

    const char* khg = (const char*)(ksp + (long)b * 2 * CD * NN) + (long)h * 64 * (NN * 2);
    const char* klg = khg + (long)CD * NN * 2;
    const char* vhg = (const char*)(qkv + ((long)b * OC3 + 2L * CD) * NN) + (long)h * 64 * (NN * 2);
    const char* vlg = vhg + (long)CD * NN * 2;
    const char* gw = (w == 0) ? khg : (w == 1) ? klg : (w == 2) ? vhg : vlg;

    int cl = (lane & 3) ^ ((lane >> 3) & 3);
    char* larr = (char*)&lds[0][0] + w * 4096;
    char* L = (char*)&lds[0][0];
    int cp16 = ((lane >> 4) ^ (((lane & 15) >> 1) & 3)) * 16;
    int lr = lane & 15;

    f32x4 acc[4];
    #pragma unroll
    for (int i = 0; i < 4; ++i) acc[i] = (f32x4){0.f, 0.f, 0.f, 0.f};

    for (int ks = 0; ks < 8; ++ks) {
        long kbyte = ((long)sp * 256 + ks * 32) * 2;
        #pragma unroll
        for (int c = 0; c < 4; ++c)
            gload_lds16(gw + (long)(c * 16 + (lane >> 2)) * (NN * 2) + kbyte + (long)cl * 16,
                        larr + c * 1024 + lane * 16);
        asm volatile("s_waitcnt vmcnt(0)" ::: "memory");
        __syncthreads();

        half8 ah[4], al[4], bhf, blf;
        #pragma unroll
        for (int i = 0; i < 4; ++i) {
            ah[i] = *(const half8*)(L + 0 * 4096 + (i * 16 + lr) * 64 + cp16);
            al[i] = *(const half8*)(L + 1 * 4096 + (i * 16 + lr) * 64 + cp16);
        }
        bhf = *(const half8*)(L + 2 * 4096 + (w * 16 + lr) * 64 + cp16);
        blf = *(const half8*)(L + 3 * 4096 + (w * 16 + lr) * 64 + cp16);
        #pragma unroll
        for (int i = 0; i < 4; ++i) {
            acc[i] = __builtin_amdgcn_mfma_f32_16x16x32_f16(ah[i], bhf, acc[i], 0, 0, 0);
            acc[i] = __builtin_amdgcn_mfma_f32_16x16x32_f16(ah[i], blf, acc[i], 0, 0, 0);
            acc[i] = __builtin_amdgcn_mfma_f32_16x16x32_f16(al[i], bhf, acc[i], 0, 0, 0);
        }
        __syncthreads();
    }

    float* op = ctxp + ((long)bh * NSPLIT + sp) * 4096;
    #pragma unroll
    for (int i = 0; i < 4; ++i)
        #pragma unroll
        for (int r = 0; r < 4; ++r)
            op[(i * 16 + (lane >> 4) * 4 + r) * 64 + w * 16 + lr] = acc[i][r];
}

// ---------------------------------------------------------------------------
// reduce partials in fp64; undo scales: /(2^12 * 2^4) and /N  => * 2^-28
// ---------------------------------------------------------------------------
__global__ __launch_bounds__(256) void context_reduce_kernel(
    const float* __restrict__ ctxp, float* __restrict__ ctx)
{
    int idx = blockIdx.x * 256 + threadIdx.x;
    int bh = idx >> 12;
    int de = idx & 4095;
    double s = 0.0;
    #pragma unroll
    for (int sp = 0; sp < NSPLIT; ++sp)
        s += (double)ctxp[((long)bh * NSPLIT + sp) * 4096 + de];
    ctx[idx] = (float)(s * (1.0 / 268435456.0));
}

// ---------------------------------------------------------------------------
// fold w_out into per-batch M (row-major [c][hd]) — LDS-tiled:
// block = (c-tile 128, bh); ctx[b,h] (64x64) staged once in LDS (65-pad).
// ---------------------------------------------------------------------------
__global__ __launch_bounds__(256) void fold_wout_kernel(
    const float* __restrict__ w_out, const float* __restrict__ ctx,
    float* __restrict__ Mf)
{
    __shared__ float cl[64][65];
    int ct = blockIdx.x;               // c-tile 0..3
    int bh = blockIdx.y;               // b*8+h
    int b = bh >> 3, h = bh & 7;
    int t = threadIdx.x;
    const float* cp = ctx + (long)bh * 4096;
    #pragma unroll
    for (int i = 0; i < 16; ++i) {
        int o = t + i * 256;
        cl[o >> 6][o & 63] = cp[o];
    }
    __syncthreads();

    int d = t & 63, tc = t >> 6;       // 4 c-subgroups of 32
    #pragma unroll 4
    for (int ci = 0; ci < 32; ++ci) {
        int c = ct * 128 + tc * 32 + ci;
        const float* wr = w_out + (long)c * CD + h * DD;
        float s = 0.f;
        #pragma unroll
        for (int e = 0; e < 64; ++e) s += wr[e] * cl[d][e];
        Mf[((long)b * CD + c) * CD + h * DD + d] = s;
    }
}

// ---------------------------------------------------------------------------
// per-batch max|M| two-stage: 32 partial blocks per batch, then final.
// ---------------------------------------------------------------------------
__global__ __launch_bounds__(256) void max_m_part_kernel(
    const float* __restrict__ Mf, float* __restrict__ part)
{
    int blk = blockIdx.x;              // 256 blocks: b = blk>>5, sub = blk&31
    int b = blk >> 5, sub = blk & 31;
    const float4* p = (const float4*)(Mf + (long)b * CD * CD) + (long)sub * 2048;
    float mx = 0.f;
    for (int i = threadIdx.x; i < 2048; i += 256) {
        float4 v = p[i];
        mx = fmaxf(mx, fmaxf(fmaxf(fabsf(v.x), fabsf(v.y)),
                             fmaxf(fabsf(v.z), fabsf(v.w))));
    }
    __shared__ float red[256];
    red[threadIdx.x] = mx; __syncthreads();
    for (int off = 128; off > 0; off >>= 1) {
        if (threadIdx.x < off) red[threadIdx.x] = fmaxf(red[threadIdx.x], red[threadIdx.x + off]);
        __syncthreads();
    }
    if (threadIdx.x == 0) part[blk] = red[0];
}

__global__ __launch_bounds__(64) void max_m_final_kernel(
    const float* __restrict__ part, float* __restrict__ scl)
{
    int b = threadIdx.x;
    if (b < 8) {
        float m = 0.f;
        #pragma unroll
        for (int i = 0; i < 32; ++i) m = fmaxf(m, part[b * 32 + i]);
        int e = (m > 1e-30f) ? ilogbf(m) : 0;
        scl[b] = ldexpf(1.f, 10 - e);
        scl[8 + b] = ldexpf(1.f, e - 10);
    }
}

// ---------------------------------------------------------------------------
// split M fp32 -> mh/ml f16 with per-batch scale
// ---------------------------------------------------------------------------
__global__ __launch_bounds__(256) void split_m_kernel(
    const float* __restrict__ Mf, const float* __restrict__ scl,
    f16* __restrict__ mh, f16* __restrict__ ml)
{
    int idx = blockIdx.x * 256 + threadIdx.x;   // BB*CD*CD/4 float4s
    float s = scl[idx >> 16];                   // 65536 float4s per batch
    float4 v = ((const float4*)Mf)[idx];
    float a[4] = {v.x, v.y, v.z, v.w};
    half4v h, l;
    #pragma unroll
    for (int i = 0; i < 4; ++i) {
        float tval = a[i] * s;
        f16 hv = (f16)tval;
        h[i] = hv;
        l[i] = (f16)(tval - (float)hv);
    }
    *(half4v*)(&mh[(long)idx * 4]) = h;
    *(half4v*)(&ml[(long)idx * 4]) = l;
}

// ---------------------------------------------------------------------------
// channel LayerNorm over c=512 (stride NN), fp64 stats, values reg-cached.
// ---------------------------------------------------------------------------
__global__ __launch_bounds__(256) void layernorm_kernel(
    const float* __restrict__ qkv, const float* __restrict__ g,
    float* __restrict__ out)
{
    int t = threadIdx.x;
    int tn = t & 31, cy = t >> 5;              // col-in-block, c-group
    long col = (long)blockIdx.x * 32 + tn;     // 0..32767
    int n = (int)(col & (NN - 1));
    int b = (int)(col >> 12);
    const float* base = qkv + (long)b * OC3 * NN + (long)CD * NN + n;

    float v[64];
    double s = 0.0, ss = 0.0;
    #pragma unroll
    for (int i = 0; i < 64; ++i) {
        v[i] = base[(long)(cy * 64 + i) * NN];
        s += (double)v[i];
        ss += (double)v[i] * (double)v[i];
    }

    __shared__ double rs[8][32], rss[8][32];
    rs[cy][tn] = s; rss[cy][tn] = ss;
    __syncthreads();
    __shared__ float mb[32], ib[32];
    if (cy == 0) {
        double S = 0.0, SS = 0.0;
        #pragma unroll
        for (int j = 0; j < 8; ++j) { S += rs[j][tn]; SS += rss[j][tn]; }
        double mean = S * (1.0 / CD);
        double var = SS * (1.0 / CD) - mean * mean;
        mb[tn] = (float)mean;
        ib[tn] = (float)(1.0 / sqrt(var + 1e-5));
    }
    __syncthreads();
    float m = mb[tn], iv = ib[tn];

    float* oc = out + (long)b * CD * NN + n;
    #pragma unroll
    for (int i = 0; i < 64; ++i)
        oc[(long)(cy * 64 + i) * NN] = (v[i] - m) * iv * g[cy * 64 + i];
}

// ---------------------------------------------------------------------------
extern "C" void kernel_launch(void* const* d_in, const int* in_sizes, int n_in,
                              void* d_out, int out_size, void* d_ws, size_t ws_size,
                              hipStream_t stream)
{
    const float* x     = (const float*)d_in[0];
    const float* w_qkv = (const float*)d_in[1];
    const float* w_out = (const float*)d_in[2];
    const float* b_out = (const float*)d_in[3];
    const float* g     = (const float*)d_in[4];
    float* out = (float*)d_out;

    float* ws   = (float*)d_ws;
    float* qkv  = ws;                                      // 50,331,648 f
    float* ctxp = qkv + (long)BB * OC3 * NN;               //  4,194,304 f (reused for Mf)
    float* ctx  = ctxp + (long)BB * HH * NSPLIT * DD * DD; //    262,144 f
    f16*   mh   = (f16*)(ctx + (long)BB * HH * DD * DD);   //  2,097,152 h
    f16*   ml   = mh + (long)BB * CD * CD;                 //  2,097,152 h
    f16*   wh   = (f16*)(ml + (long)BB * CD * CD);         //    786,432 h
    f16*   wl   = wh + (long)OC3 * CD;                     //    786,432 h
    float* scl  = (float*)(wl + (long)OC3 * CD);           //         16 f
    float* part = scl + 16;                                //        256 f
    float* Mf   = ctxp;                                    // ctxp dead by then

    // d_out as scratch, phase-ordered: xth/xtl -> ksp (kh/kl) -> final out
    f16* xth = (f16*)d_out;
    f16* xtl = xth + (long)BB * NN * CD;
    f16* ksp = (f16*)d_out;          // after xth/xtl consumed by qkv GEMM

    // 0) operand splits
    split_w_kernel<<<(OC3 * CD / 4) / 256, 256, 0, stream>>>(w_qkv, wh, wl);
    split_x_kernel<<<dim3(NN / 64, CD / 64, BB), 256, 0, stream>>>(x, xth, xtl);

    // 1) qkv = w_qkv @ x via split-f16 MFMA, fused epilogues (q softmax+split,
    //    k fp32, v split). 256x256 tiles, 512 threads.
    mfma_gemm_kernel<<<dim3(NN / 256, OC3 / 256, BB), 512, 0, stream>>>(
        wh, wl, 0L, xth, xtl, (long)NN * CD,
        qkv, (long)OC3 * NN, NN, 1.0f / 1024.0f);

    // 2) k softmax -> split-f16 k_s (x4096) into d_out
    softmax_k_kernel<<<BB * CD, 256, 0, stream>>>(qkv, ksp);

    // 3) context partials via MFMA (pre-split k and v) + fp64 reduce
    ctx_mfma_kernel<<<dim3(NSPLIT, BB * HH), 256, 0, stream>>>(ksp, qkv, ctxp);
    context_reduce_kernel<<<(BB * HH * DD * DD) / 256, 256, 0, stream>>>(ctxp, ctx);

    // 4) M = fold(w_out, ctx) -> Mf (ws); pow2 scale; f16 split
    fold_wout_kernel<<<dim3(4, BB * HH), 256, 0, stream>>>(w_out, ctx, Mf);
    max_m_part_kernel<<<256, 256, 0, stream>>>(Mf, part);
    max_m_final_kernel<<<1, 64, 0, stream>>>(part, scl);
    split_m_kernel<<<(BB * CD * CD / 4) / 256, 256, 0, stream>>>(Mf, scl, mh, ml);

    // 5) y = M_b @ q_s + b_out via split-f16 MFMA (128x128 tiles) -> dead k
    //    region of qkv.  B operand = qh/ql in q region ([n][512] layout).
    mfma_gemm128_kernel<<<dim3(NN / 128, CD / 128, BB), 256, 0, stream>>>(
        mh, ml, (long)CD * CD,
        (const f16*)qkv, (const f16*)qkv + (long)CD * NN, (long)OC3 * NN * 2,
        qkv + (long)CD * NN, (long)OC3 * NN, NN, b_out, scl + 8, 1.0f / 256.0f);

    // 6) channel LayerNorm -> d_out (overwrites ksp scratch)
    layernorm_kernel<<<(BB * NN) / 32, 256, 0, stream>>>(qkv, g, out);
}

// Round 16
// 376.537 us; speedup vs baseline: 1.0759x; 1.0129x over previous
//
#include <hip/hip_runtime.h>
#include <math.h>

// Problem constants
#define BB 8
#define NN 4096      // 64*64 tokens
#define CD 512       // channels
#define HH 8
#define DD 64
#define OC3 1536     // 3*hidden
#define NSPLIT 16

typedef _Float16 f16;
typedef _Float16 half8 __attribute__((ext_vector_type(8)));
typedef _Float16 half4v __attribute__((ext_vector_type(4)));
typedef float f32x4 __attribute__((ext_vector_type(4)));

__device__ __forceinline__ void gload_lds16(const void* g, void* l) {
    __builtin_amdgcn_global_load_lds(
        (const __attribute__((address_space(1))) unsigned int*)g,
        (__attribute__((address_space(3))) unsigned int*)l, 16, 0, 0);
}

// ---------------------------------------------------------------------------
// split w_qkv [1536][512] f32 -> wh, wl [1536][512] f16, scaled by 64
// ---------------------------------------------------------------------------
__global__ __launch_bounds__(256) void split_w_kernel(
    const float* __restrict__ w, f16* __restrict__ wh, f16* __restrict__ wl)
{
    int idx = blockIdx.x * 256 + threadIdx.x;      // OC3*CD/4 = 196608 total
    float4 v = ((const float4*)w)[idx];
    float a[4] = {v.x, v.y, v.z, v.w};
    half4v h, l;
    #pragma unroll
    for (int i = 0; i < 4; ++i) {
        float s = a[i] * 64.f;
        f16 hh = (f16)s;
        h[i] = hh;
        l[i] = (f16)(s - (float)hh);
    }
    *(half4v*)(&wh[(long)idx * 4]) = h;
    *(half4v*)(&wl[(long)idx * 4]) = l;
}

// ---------------------------------------------------------------------------
// split + transpose x [b][512 c][4096 n] f32 -> xth, xtl [b][4096 n][512 c]
// f16, scaled by 16.  64x64 tile, half8 (16B) coalesced writes.
// ---------------------------------------------------------------------------
__global__ __launch_bounds__(256) void split_x_kernel(
    const float* __restrict__ x, f16* __restrict__ xth, f16* __restrict__ xtl)
{
    __shared__ float tile[64][65];
    int b = blockIdx.z;
    int n0 = blockIdx.x * 64, c0 = blockIdx.y * 64;
    const float* xb = x + ((long)b * CD + c0) * NN + n0;
    int t = threadIdx.x;
    int tr = t >> 6, tc = t & 63;
    #pragma unroll
    for (int i = 0; i < 16; ++i)
        tile[tr + i * 4][tc] = xb[(long)(tr + i * 4) * NN + tc];
    __syncthreads();

    int nl = t >> 3, ck = (t & 7) * 8;
    long obase = ((long)b * NN + n0) * CD + c0;
    #pragma unroll
    for (int p = 0; p < 2; ++p) {
        int n = nl + p * 32;
        half8 h, l;
        #pragma unroll
        for (int j = 0; j < 8; ++j) {
            float s = tile[ck + j][n] * 16.f;
            f16 hv = (f16)s;
            h[j] = hv;
            l[j] = (f16)(s - (float)hv);
        }
        *(half8*)(&xth[obase + (long)n * CD + ck]) = h;
        *(half8*)(&xtl[obase + (long)n * CD + ck]) = l;
    }
}

// ---------------------------------------------------------------------------
// qkv GEMM: split-f16 MFMA, K=512. 3 products hh+hl+lh, fp32 accum.
// Block 512 thr = 8 waves (2Mx4N), tile 256x256, wave tile 128x64, KT=32,
// 2-phase dbuf, LDS 128 KB.  (R12-verified best: 153 us, MfmaUtil 46%.)
//   m0 <  512 : q third -> fused softmax-over-d -> split-f16 (p*32) into
//               q region of qkv, [n][512] layout
//   m0 >= 1024: v third -> split-f16 (x16) into qkv's v region
//   else      : k third -> fp32
// ---------------------------------------------------------------------------
#define AR  16384   // per-operand-array LDS bytes (256 rows x 64B)
#define BUF 65536   // per-dbuf bytes

#define STAGE(Lb, k0s)  do {                                                   \
    long kb_ = (long)(k0s) * 2;                                                \
    _Pragma("unroll")                                                          \
    for (int c_ = 0; c_ < 2; ++c_) {                                           \
        long rowoff_ = (long)(rb0 + c_ * 16) * 1024;                           \
        long ldsoff_ = (long)(rb0 + c_ * 16) * 64;                             \
        gload_lds16(gA_h + rowoff_ + kb_ + g_lane, (Lb) + 0 * AR + ldsoff_);   \
        gload_lds16(gA_l + rowoff_ + kb_ + g_lane, (Lb) + 1 * AR + ldsoff_);   \
        gload_lds16(gB_h + rowoff_ + kb_ + g_lane, (Lb) + 2 * AR + ldsoff_);   \
        gload_lds16(gB_l + rowoff_ + kb_ + g_lane, (Lb) + 3 * AR + ldsoff_);   \
    } } while (0)

__global__ __launch_bounds__(512, 2) void mfma_gemm_kernel(
    const f16* __restrict__ Ah, const f16* __restrict__ Al, long sA,
    const f16* __restrict__ Bh, const f16* __restrict__ Bl, long sB,
    float* __restrict__ Cp, long sC, int ldC, float base_sc)
{
    __shared__ f16 lds[2][4][256 * 32];  // 128 KB
    int bz = blockIdx.z;
    int n0 = blockIdx.x * 256, m0 = blockIdx.y * 256;
    int t = threadIdx.x;
    int lane = t & 63, wid = t >> 6;     // 8 waves
    int wy = wid >> 2, wx = wid & 3;     // 2 (M) x 4 (N)

    int cl = (lane & 3) ^ ((lane >> 3) & 3);
    long g_lane = (long)(lane >> 2) * 1024 + (long)cl * 16;

    const char* gA_h = (const char*)(Ah + bz * sA) + (long)m0 * 1024;
    const char* gA_l = (const char*)(Al + bz * sA) + (long)m0 * 1024;
    const char* gB_h = (const char*)(Bh + bz * sB) + (long)n0 * 1024;
    const char* gB_l = (const char*)(Bl + bz * sB) + (long)n0 * 1024;

    char* L0 = (char*)&lds[0][0][0];
    int rb0 = wid * 32;

    int cp = (lane >> 4) ^ (((lane & 15) >> 1) & 3);
    long offA = (long)(wy * 128 + (lane & 15)) * 64 + (long)cp * 16;
    long offB = (long)(wx * 64 + (lane & 15)) * 64 + (long)cp * 16;

    f32x4 acc[8][4];
    #pragma unroll
    for (int i = 0; i < 8; ++i)
        #pragma unroll
        for (int j = 0; j < 4; ++j)
            acc[i][j] = (f32x4){0.f, 0.f, 0.f, 0.f};

    STAGE(L0, 0);
    asm volatile("s_waitcnt vmcnt(0)" ::: "memory");
    __syncthreads();

    for (int s = 0; s < 16; ++s) {
        char* Lc = L0 + ((s & 1) ? BUF : 0);
        if (s < 15) {
            char* Ln = L0 + (((s + 1) & 1) ? BUF : 0);
            STAGE(Ln, (s + 1) * 32);
        }

        half8 ah[8], al[8];
        #pragma unroll
        for (int i = 0; i < 8; ++i) {
            ah[i] = *(const half8*)(Lc + 0 * AR + offA + i * 1024);
            al[i] = *(const half8*)(Lc + 1 * AR + offA + i * 1024);
        }
        #pragma unroll
        for (int j = 0; j < 4; ++j) {
            half8 bh = *(const half8*)(Lc + 2 * AR + offB + j * 1024);
            half8 bl = *(const half8*)(Lc + 3 * AR + offB + j * 1024);
            #pragma unroll
            for (int i = 0; i < 8; ++i) {
                acc[i][j] = __builtin_amdgcn_mfma_f32_16x16x32_f16(ah[i], bh, acc[i][j], 0, 0, 0);
                acc[i][j] = __builtin_amdgcn_mfma_f32_16x16x32_f16(ah[i], bl, acc[i][j], 0, 0, 0);
                acc[i][j] = __builtin_amdgcn_mfma_f32_16x16x32_f16(al[i], bh, acc[i][j], 0, 0, 0);
            }
        }

        asm volatile("s_waitcnt vmcnt(0)" ::: "memory");
        __syncthreads();
    }

    // C/D layout: col = lane&15, row = (lane>>4)*4 + reg
    int colb = n0 + wx * 64 + (lane & 15);
    int rowb = m0 + wy * 128 + ((lane >> 4) << 2);

    if (m0 < 512) {
        // q third: wave's 128 rows = heads h0, h0+1. Fused softmax over d +
        // split-f16 (p*32 = q_s*256), [n][512] layout.
        int h0 = (m0 >> 6) + wy * 2;
        f16* qh_b = (f16*)(Cp + (long)bz * sC);
        f16* ql_b = qh_b + (long)CD * NN;
        #pragma unroll
        for (int i = 0; i < 8; ++i)
            #pragma unroll
            for (int j = 0; j < 4; ++j)
                #pragma unroll
                for (int r = 0; r < 4; ++r)
                    acc[i][j][r] *= base_sc;
        #pragma unroll
        for (int j = 0; j < 4; ++j) {
            long nj = colb + j * 16;
            #pragma unroll
            for (int g = 0; g < 2; ++g) {
                float mx = -INFINITY;
                #pragma unroll
                for (int di = 0; di < 4; ++di)
                    #pragma unroll
                    for (int r = 0; r < 4; ++r)
                        mx = fmaxf(mx, acc[g * 4 + di][j][r]);
                mx = fmaxf(mx, __shfl_xor(mx, 16));
                mx = fmaxf(mx, __shfl_xor(mx, 32));
                float sum = 0.f;
                #pragma unroll
                for (int di = 0; di < 4; ++di)
                    #pragma unroll
                    for (int r = 0; r < 4; ++r) {
                        float e = expf(acc[g * 4 + di][j][r] - mx);
                        acc[g * 4 + di][j][r] = e;
                        sum += e;
                    }
                sum += __shfl_xor(sum, 16);
                sum += __shfl_xor(sum, 32);
                float rj = 32.f / sum;
                long off = nj * CD + (h0 + g) * 64 + ((lane >> 4) << 2);
                #pragma unroll
                for (int di = 0; di < 4; ++di) {
                    half4v hh, ll;
                    #pragma unroll
                    for (int r = 0; r < 4; ++r) {
                        float v = acc[g * 4 + di][j][r] * rj;
                        f16 hv = (f16)v;
                        hh[r] = hv;
                        ll[r] = (f16)(v - (float)hv);
                    }
                    *(half4v*)(qh_b + off + di * 16) = hh;
                    *(half4v*)(ql_b + off + di * 16) = ll;
                }
            }
        }
        return;
    }

    if (m0 >= 1024) {
        // v third: emit split-f16 (value = v_true * 16) into qkv's v region
        f16* vhp = (f16*)(Cp + (long)bz * sC + 2L * CD * NN);
        f16* vlp = vhp + (long)CD * NN;
        float vsc = base_sc * 16.f;
        #pragma unroll
        for (int i = 0; i < 8; ++i)
            #pragma unroll
            for (int j = 0; j < 4; ++j)
                #pragma unroll
                for (int r = 0; r < 4; ++r) {
                    long row = rowb + i * 16 + r - 1024;
                    float val = acc[i][j][r] * vsc;
                    f16 hv = (f16)val;
                    vhp[row * NN + colb + j * 16] = hv;
                    vlp[row * NN + colb + j * 16] = (f16)(val - (float)hv);
                }
        return;
    }

    // k third: fp32
    float* outp = Cp + bz * sC;
    #pragma unroll
    for (int i = 0; i < 8; ++i)
        #pragma unroll
        for (int j = 0; j < 4; ++j)
            #pragma unroll
            for (int r = 0; r < 4; ++r) {
                int row = rowb + i * 16 + r;
                outp[(long)row * ldC + colb + j * 16] = acc[i][j][r] * base_sc;
            }
}

// ---------------------------------------------------------------------------
// GEMM2: split-f16 MFMA, K=512, 128x128 tile, 4 waves 2x2, wave 64x64,
// 2-phase dbuf, 64 KB LDS (2 blocks/CU).  C = acc*base_sc*inv_sc[bz] + bias.
// ---------------------------------------------------------------------------
#define AR2  8192
#define BUF2 32768

#define STAGE2(Lb, k0s)  do {                                                  \
    long kb_ = (long)(k0s) * 2;                                                \
    _Pragma("unroll")                                                          \
    for (int c_ = 0; c_ < 2; ++c_) {                                           \
        long rowoff_ = (long)(rb0 + c_ * 16) * 1024;                           \
        long ldsoff_ = (long)(rb0 + c_ * 16) * 64;                             \
        gload_lds16(gA_h + rowoff_ + kb_ + g_lane, (Lb) + 0 * AR2 + ldsoff_);  \
        gload_lds16(gA_l + rowoff_ + kb_ + g_lane, (Lb) + 1 * AR2 + ldsoff_);  \
        gload_lds16(gB_h + rowoff_ + kb_ + g_lane, (Lb) + 2 * AR2 + ldsoff_);  \
        gload_lds16(gB_l + rowoff_ + kb_ + g_lane, (Lb) + 3 * AR2 + ldsoff_);  \
    } } while (0)

__global__ __launch_bounds__(256) void mfma_gemm128_kernel(
    const f16* __restrict__ Ah, const f16* __restrict__ Al, long sA,
    const f16* __restrict__ Bh, const f16* __restrict__ Bl, long sB,
    float* __restrict__ Cp, long sC, int ldC,
    const float* __restrict__ bias, const float* __restrict__ inv_sc,
    float base_sc)
{
    __shared__ f16 lds[2][4][128 * 32];  // 64 KB
    int bz = blockIdx.z;
    int n0 = blockIdx.x * 128, m0 = blockIdx.y * 128;
    int t = threadIdx.x;
    int lane = t & 63, wid = t >> 6;
    int wy = wid >> 1, wx = wid & 1;

    int cl = (lane & 3) ^ ((lane >> 3) & 3);
    long g_lane = (long)(lane >> 2) * 1024 + (long)cl * 16;

    const char* gA_h = (const char*)(Ah + bz * sA) + (long)m0 * 1024;
    const char* gA_l = (const char*)(Al + bz * sA) + (long)m0 * 1024;
    const char* gB_h = (const char*)(Bh + bz * sB) + (long)n0 * 1024;
    const char* gB_l = (const char*)(Bl + bz * sB) + (long)n0 * 1024;

    char* L0 = (char*)&lds[0][0][0];
    int rb0 = wid * 32;

    int cp = (lane >> 4) ^ (((lane & 15) >> 1) & 3);
    long offA = (long)(wy * 64 + (lane & 15)) * 64 + (long)cp * 16;
    long offB = (long)(wx * 64 + (lane & 15)) * 64 + (long)cp * 16;

    f32x4 acc[4][4];
    #pragma unroll
    for (int i = 0; i < 4; ++i)
        #pragma unroll
        for (int j = 0; j < 4; ++j)
            acc[i][j] = (f32x4){0.f, 0.f, 0.f, 0.f};

    STAGE2(L0, 0);
    asm volatile("s_waitcnt vmcnt(0)" ::: "memory");
    __syncthreads();

    for (int s = 0; s < 16; ++s) {
        char* Lc = L0 + ((s & 1) ? BUF2 : 0);
        if (s < 15) {
            char* Ln = L0 + (((s + 1) & 1) ? BUF2 : 0);
            STAGE2(Ln, (s + 1) * 32);
        }

        half8 ah[4], al[4], bh[4], bl[4];
        #pragma unroll
        for (int i = 0; i < 4; ++i) {
            ah[i] = *(const half8*)(Lc + 0 * AR2 + offA + i * 1024);
            al[i] = *(const half8*)(Lc + 1 * AR2 + offA + i * 1024);
            bh[i] = *(const half8*)(Lc + 2 * AR2 + offB + i * 1024);
            bl[i] = *(const half8*)(Lc + 3 * AR2 + offB + i * 1024);
        }
        #pragma unroll
        for (int i = 0; i < 4; ++i)
            #pragma unroll
            for (int j = 0; j < 4; ++j) {
                acc[i][j] = __builtin_amdgcn_mfma_f32_16x16x32_f16(ah[i], bh[j], acc[i][j], 0, 0, 0);
                acc[i][j] = __builtin_amdgcn_mfma_f32_16x16x32_f16(ah[i], bl[j], acc[i][j], 0, 0, 0);
                acc[i][j] = __builtin_amdgcn_mfma_f32_16x16x32_f16(al[i], bh[j], acc[i][j], 0, 0, 0);
            }

        asm volatile("s_waitcnt vmcnt(0)" ::: "memory");
        __syncthreads();
    }

    int colb = n0 + wx * 64 + (lane & 15);
    int rowb = m0 + wy * 64 + ((lane >> 4) << 2);
    float* outp = Cp + bz * sC;
    float mult = base_sc * (inv_sc ? inv_sc[bz] : 1.f);
    #pragma unroll
    for (int i = 0; i < 4; ++i)
        #pragma unroll
        for (int j = 0; j < 4; ++j)
            #pragma unroll
            for (int r = 0; r < 4; ++r) {
                int row = rowb + i * 16 + r;
                float bb = bias ? bias[row] : 0.f;
                outp[(long)row * ldC + colb + j * 16] = acc[i][j][r] * mult + bb;
            }
}

// ---------------------------------------------------------------------------
// k softmax row stats: per (b,hd) row of k (4096 contiguous) compute
// mx and inv = 4096/sum.  (R9-verified.)
// ---------------------------------------------------------------------------
__global__ __launch_bounds__(256) void k_rowstat_kernel(
    const float* __restrict__ qkv, float* __restrict__ statmx,
    float* __restrict__ statinv)
{
    int row = blockIdx.x;              // b*512 + hd
    int b = row >> 9;
    int hd = row & (CD - 1);
    const float* base = qkv + ((long)b * OC3 + CD + hd) * NN;
    int t = threadIdx.x;

    float v[16];
    #pragma unroll
    for (int i = 0; i < 16; ++i) v[i] = base[t + i * 256];

    __shared__ float red[256];
    float mx = -INFINITY;
    #pragma unroll
    for (int i = 0; i < 16; ++i) mx = fmaxf(mx, v[i]);
    red[t] = mx; __syncthreads();
    for (int off = 128; off > 0; off >>= 1) {
        if (t < off) red[t] = fmaxf(red[t], red[t + off]);
        __syncthreads();
    }
    mx = red[0]; __syncthreads();

    float s = 0.f;
    #pragma unroll
    for (int i = 0; i < 16; ++i) {
        v[i] = expf(v[i] - mx);
        s += v[i];
    }
    red[t] = s; __syncthreads();
    for (int off = 128; off > 0; off >>= 1) {
        if (t < off) red[t] += red[t + off];
        __syncthreads();
    }
    if (t == 0) {
        statmx[row] = mx;
        statinv[row] = 4096.f / red[0];   // k_s scaled by 2^12 for f16 split
    }
}

// ---------------------------------------------------------------------------
// context partials via split-f16 MFMA with FUSED k-softmax (R9-verified):
// per (bh, sp) block: acc[64 d][64 e] = sum over 256 n of (k_s*2^12)(v*2^4).
// k staged as raw f32 (8-chunk XOR swizzle), exp+split applied in registers;
// v from qkv's v region (pre-split f16).
// ---------------------------------------------------------------------------
__global__ __launch_bounds__(256) void ctx_mfma_kernel(
    const float* __restrict__ qkv, const float* __restrict__ statmx,
    const float* __restrict__ statinv, float* __restrict__ ctxp)
{
    __shared__ char lds[16384];          // k f32 8KB | vh 4KB | vl 4KB
    int sp = blockIdx.x;                 // K-split 0..15
    int bh = blockIdx.y;                 // 0..63
    int b = bh >> 3, h = bh & 7;
    int t = threadIdx.x, lane = t & 63, w = t >> 6;

    const char* kg = (const char*)(qkv + ((long)b * OC3 + CD + (long)h * 64) * NN);
    const char* vhg = (const char*)(qkv + ((long)b * OC3 + 2L * CD) * NN) + (long)h * 64 * (NN * 2);
    const char* vlg = vhg + (long)CD * NN * 2;

    int lr = lane & 15, hi = lane >> 4;
    float mx[4], inv[4];
    #pragma unroll
    for (int i = 0; i < 4; ++i) {
        int ridx = b * CD + h * 64 + i * 16 + lr;
        mx[i] = statmx[ridx];
        inv[i] = statinv[ridx];
    }

    int cl = (lane & 3) ^ ((lane >> 3) & 3);
    int cp16 = (hi ^ ((lr >> 1) & 3)) * 16;

    int ksrow = (lane >> 3);
    int ksc = lane & 7;

    f32x4 acc[4];
    #pragma unroll
    for (int i = 0; i < 4; ++i) acc[i] = (f32x4){0.f, 0.f, 0.f, 0.f};

    int s7 = lr & 7;

    for (int ks = 0; ks < 8; ++ks) {
        int n0 = sp * 256 + ks * 32;
        if (w < 2) {
            #pragma unroll
            for (int it2 = 0; it2 < 4; ++it2) {
                int it = w * 4 + it2;
                int r = it * 8 + ksrow;
                gload_lds16(kg + (long)r * (NN * 4) + (long)n0 * 4 + ((ksc ^ (r & 7)) << 4),
                            lds + it * 1024 + lane * 16);
            }
        } else {
            const char* gv = (w == 2) ? vhg : vlg;
            char* lv = lds + 8192 + (w - 2) * 4096;
            #pragma unroll
            for (int c2 = 0; c2 < 4; ++c2)
                gload_lds16(gv + (long)(c2 * 16 + (lane >> 2)) * (NN * 2) + (long)n0 * 2 + (long)cl * 16,
                            lv + c2 * 1024 + lane * 16);
        }
        asm volatile("s_waitcnt vmcnt(0)" ::: "memory");
        __syncthreads();

        half8 ah[4], al[4];
        #pragma unroll
        for (int i = 0; i < 4; ++i) {
            int row = i * 16 + lr;
            const char* rb = lds + row * 128;
            f32x4 a0 = *(const f32x4*)(rb + (((2 * hi) ^ s7) << 4));
            f32x4 a1 = *(const f32x4*)(rb + (((2 * hi + 1) ^ s7) << 4));
            #pragma unroll
            for (int j = 0; j < 8; ++j) {
                float kv = (j < 4) ? a0[j] : a1[j - 4];
                float e = expf(kv - mx[i]) * inv[i];
                f16 hv = (f16)e;
                ah[i][j] = hv;
                al[i][j] = (f16)(e - (float)hv);
            }
        }
        half8 bhf = *(const half8*)(lds + 8192 + (w * 16 + lr) * 64 + cp16);
        half8 blf = *(const half8*)(lds + 12288 + (w * 16 + lr) * 64 + cp16);
        #pragma unroll
        for (int i = 0; i < 4; ++i) {
            acc[i] = __builtin_amdgcn_mfma_f32_16x16x32_f16(ah[i], bhf, acc[i], 0, 0, 0);
            acc[i] = __builtin_amdgcn_mfma_f32_16x16x32_f16(ah[i], blf, acc[i], 0, 0, 0);
            acc[i] = __builtin_amdgcn_mfma_f32_16x16x32_f16(al[i], bhf, acc[i], 0, 0, 0);
        }
        __syncthreads();
    }

    float* op = ctxp + ((long)bh * NSPLIT + sp) * 4096;
    #pragma unroll
    for (int i = 0; i < 4; ++i)
        #pragma unroll
        for (int r = 0; r < 4; ++r)
            op[(i * 16 + hi * 4 + r) * 64 + w * 16 + lr] = acc[i][r];
}

// ---------------------------------------------------------------------------
// reduce partials in fp64; undo scales: /(2^12 * 2^4) and /N  => * 2^-28
// ---------------------------------------------------------------------------
__global__ __launch_bounds__(256) void context_reduce_kernel(
    const float* __restrict__ ctxp, float* __restrict__ ctx)
{
    int idx = blockIdx.x * 256 + threadIdx.x;
    int bh = idx >> 12;
    int de = idx & 4095;
    double s = 0.0;
    #pragma unroll
    for (int sp = 0; sp < NSPLIT; ++sp)
        s += (double)ctxp[((long)bh * NSPLIT + sp) * 4096 + de];
    ctx[idx] = (float)(s * (1.0 / 268435456.0));
}

// ---------------------------------------------------------------------------
// fold w_out into per-batch M (row-major [c][hd]) — LDS-tiled (R12 version):
// block = (c-tile 128, bh); ctx[b,h] (64x64) staged once in LDS (65-pad).
// ---------------------------------------------------------------------------
__global__ __launch_bounds__(256) void fold_wout_kernel(
    const float* __restrict__ w_out, const float* __restrict__ ctx,
    float* __restrict__ Mf)
{
    __shared__ float cl[64][65];
    int ct = blockIdx.x;               // c-tile 0..3
    int bh = blockIdx.y;               // b*8+h
    int b = bh >> 3, h = bh & 7;
    int t = threadIdx.x;
    const float* cp = ctx + (long)bh * 4096;
    #pragma unroll
    for (int i = 0; i < 16; ++i) {
        int o = t + i * 256;
        cl[o >> 6][o & 63] = cp[o];
    }
    __syncthreads();

    int d = t & 63, tc = t >> 6;       // 4 c-subgroups of 32
    #pragma unroll 4
    for (int ci = 0; ci < 32; ++ci) {
        int c = ct * 128 + tc * 32 + ci;
        const float* wr = w_out + (long)c * CD + h * DD;
        float s = 0.f;
        #pragma unroll
        for (int e = 0; e < 64; ++e) s += wr[e] * cl[d][e];
        Mf[((long)b * CD + c) * CD + h * DD + d] = s;
    }
}

// ---------------------------------------------------------------------------
// per-batch max|M| two-stage: 32 partial blocks per batch, then final.
// ---------------------------------------------------------------------------
__global__ __launch_bounds__(256) void max_m_part_kernel(
    const float* __restrict__ Mf, float* __restrict__ part)
{
    int blk = blockIdx.x;              // 256 blocks: b = blk>>5, sub = blk&31
    int b = blk >> 5, sub = blk & 31;
    const float4* p = (const float4*)(Mf + (long)b * CD * CD) + (long)sub * 2048;
    float mx = 0.f;
    for (int i = threadIdx.x; i < 2048; i += 256) {
        float4 v = p[i];
        mx = fmaxf(mx, fmaxf(fmaxf(fabsf(v.x), fabsf(v.y)),
                             fmaxf(fabsf(v.z), fabsf(v.w))));
    }
    __shared__ float red[256];
    red[threadIdx.x] = mx; __syncthreads();
    for (int off = 128; off > 0; off >>= 1) {
        if (threadIdx.x < off) red[threadIdx.x] = fmaxf(red[threadIdx.x], red[threadIdx.x + off]);
        __syncthreads();
    }
    if (threadIdx.x == 0) part[blk] = red[0];
}

__global__ __launch_bounds__(64) void max_m_final_kernel(
    const float* __restrict__ part, float* __restrict__ scl)
{
    int b = threadIdx.x;
    if (b < 8) {
        float m = 0.f;
        #pragma unroll
        for (int i = 0; i < 32; ++i) m = fmaxf(m, part[b * 32 + i]);
        int e = (m > 1e-30f) ? ilogbf(m) : 0;
        scl[b] = ldexpf(1.f, 10 - e);
        scl[8 + b] = ldexpf(1.f, e - 10);
    }
}

// ---------------------------------------------------------------------------
// split M fp32 -> mh/ml f16 with per-batch scale
// ---------------------------------------------------------------------------
__global__ __launch_bounds__(256) void split_m_kernel(
    const float* __restrict__ Mf, const float* __restrict__ scl,
    f16* __restrict__ mh, f16* __restrict__ ml)
{
    int idx = blockIdx.x * 256 + threadIdx.x;   // BB*CD*CD/4 float4s
    float s = scl[idx >> 16];                   // 65536 float4s per batch
    float4 v = ((const float4*)Mf)[idx];
    float a[4] = {v.x, v.y, v.z, v.w};
    half4v h, l;
    #pragma unroll
    for (int i = 0; i < 4; ++i) {
        float tval = a[i] * s;
        f16 hv = (f16)tval;
        h[i] = hv;
        l[i] = (f16)(tval - (float)hv);
    }
    *(half4v*)(&mh[(long)idx * 4]) = h;
    *(half4v*)(&ml[(long)idx * 4]) = l;
}

// ---------------------------------------------------------------------------
// channel LayerNorm over c=512 (stride NN), fp64 stats, values reg-cached.
// ---------------------------------------------------------------------------
__global__ __launch_bounds__(256) void layernorm_kernel(
    const float* __restrict__ qkv, const float* __restrict__ g,
    float* __restrict__ out)
{
    int t = threadIdx.x;
    int tn = t & 31, cy = t >> 5;              // col-in-block, c-group
    long col = (long)blockIdx.x * 32 + tn;     // 0..32767
    int n = (int)(col & (NN - 1));
    int b = (int)(col >> 12);
    const float* base = qkv + (long)b * OC3 * NN + (long)CD * NN + n;

    float v[64];
    double s = 0.0, ss = 0.0;
    #pragma unroll
    for (int i = 0; i < 64; ++i) {
        v[i] = base[(long)(cy * 64 + i) * NN];
        s += (double)v[i];
        ss += (double)v[i] * (double)v[i];
    }

    __shared__ double rs[8][32], rss[8][32];
    rs[cy][tn] = s; rss[cy][tn] = ss;
    __syncthreads();
    __shared__ float mb[32], ib[32];
    if (cy == 0) {
        double S = 0.0, SS = 0.0;
        #pragma unroll
        for (int j = 0; j < 8; ++j) { S += rs[j][tn]; SS += rss[j][tn]; }
        double mean = S * (1.0 / CD);
        double var = SS * (1.0 / CD) - mean * mean;
        mb[tn] = (float)mean;
        ib[tn] = (float)(1.0 / sqrt(var + 1e-5));
    }
    __syncthreads();
    float m = mb[tn], iv = ib[tn];

    float* oc = out + (long)b * CD * NN + n;
    #pragma unroll
    for (int i = 0; i < 64; ++i)
        oc[(long)(cy * 64 + i) * NN] = (v[i] - m) * iv * g[cy * 64 + i];
}

// ---------------------------------------------------------------------------
extern "C" void kernel_launch(void* const* d_in, const int* in_sizes, int n_in,
                              void* d_out, int out_size, void* d_ws, size_t ws_size,
                              hipStream_t stream)
{
    const float* x     = (const float*)d_in[0];
    const float* w_qkv = (const float*)d_in[1];
    const float* w_out = (const float*)d_in[2];
    const float* b_out = (const float*)d_in[3];
    const float* g     = (const float*)d_in[4];
    float* out = (float*)d_out;

    float* ws   = (float*)d_ws;
    float* qkv  = ws;                                      // 50,331,648 f
    float* ctxp = qkv + (long)BB * OC3 * NN;               //  4,194,304 f (reused for Mf)
    float* ctx  = ctxp + (long)BB * HH * NSPLIT * DD * DD; //    262,144 f
    f16*   mh   = (f16*)(ctx + (long)BB * HH * DD * DD);   //  2,097,152 h
    f16*   ml   = mh + (long)BB * CD * CD;                 //  2,097,152 h
    f16*   wh   = (f16*)(ml + (long)BB * CD * CD);         //    786,432 h
    f16*   wl   = wh + (long)OC3 * CD;                     //    786,432 h
    float* scl  = (float*)(wl + (long)OC3 * CD);           //         16 f
    float* part = scl + 16;                                //        256 f
    float* statmx = part + 256;                            //      4,096 f
    float* statinv = statmx + BB * CD;                     //      4,096 f
    float* Mf   = ctxp;                                    // ctxp dead by then

    // d_out as scratch: xth/xtl (consumed by qkv GEMM) -> final out
    f16* xth = (f16*)d_out;
    f16* xtl = xth + (long)BB * NN * CD;

    // 0) operand splits
    split_w_kernel<<<(OC3 * CD / 4) / 256, 256, 0, stream>>>(w_qkv, wh, wl);
    split_x_kernel<<<dim3(NN / 64, CD / 64, BB), 256, 0, stream>>>(x, xth, xtl);

    // 1) qkv = w_qkv @ x via split-f16 MFMA, fused epilogues (q softmax+split,
    //    k fp32, v split). 256x256 tiles, 512 threads.
    mfma_gemm_kernel<<<dim3(NN / 256, OC3 / 256, BB), 512, 0, stream>>>(
        wh, wl, 0L, xth, xtl, (long)NN * CD,
        qkv, (long)OC3 * NN, NN, 1.0f / 1024.0f);

    // 2) k softmax row stats only (mx, 4096/sum) — R9 fused k-path
    k_rowstat_kernel<<<BB * CD, 256, 0, stream>>>(qkv, statmx, statinv);

    // 3) context partials via MFMA with fused exp+split on k + fp64 reduce
    ctx_mfma_kernel<<<dim3(NSPLIT, BB * HH), 256, 0, stream>>>(
        qkv, statmx, statinv, ctxp);
    context_reduce_kernel<<<(BB * HH * DD * DD) / 256, 256, 0, stream>>>(ctxp, ctx);

    // 4) M = fold(w_out, ctx) -> Mf (ws); pow2 scale; f16 split
    fold_wout_kernel<<<dim3(4, BB * HH), 256, 0, stream>>>(w_out, ctx, Mf);
    max_m_part_kernel<<<256, 256, 0, stream>>>(Mf, part);
    max_m_final_kernel<<<1, 64, 0, stream>>>(part, scl);
    split_m_kernel<<<(BB * CD * CD / 4) / 256, 256, 0, stream>>>(Mf, scl, mh, ml);

    // 5) y = M_b @ q_s + b_out via split-f16 MFMA (128x128 tiles) -> dead k
    //    region of qkv.  B operand = qh/ql in q region ([n][512] layout).
    mfma_gemm128_kernel<<<dim3(NN / 128, CD / 128, BB), 256, 0, stream>>>(
        mh, ml, (long)CD * CD,
        (const f16*)qkv, (const f16*)qkv + (long)CD * NN, (long)OC3 * NN * 2,
        qkv + (long)CD * NN, (long)OC3 * NN, NN, b_out, scl + 8, 1.0f / 256.0f);

    // 6) channel LayerNorm -> d_out
    layernorm_kernel<<<(BB * NN) / 32, 256, 0, stream>>>(qkv, g, out);
}

// Round 17
// 362.836 us; speedup vs baseline: 1.1165x; 1.0378x over previous
//
#include <hip/hip_runtime.h>
#include <math.h>

// Problem constants
#define BB 8
#define NN 4096      // 64*64 tokens
#define CD 512       // channels
#define HH 8
#define DD 64
#define OC3 1536     // 3*hidden
#define NSPLIT 16

typedef _Float16 f16;
typedef _Float16 half8 __attribute__((ext_vector_type(8)));
typedef _Float16 half4v __attribute__((ext_vector_type(4)));
typedef float f32x4 __attribute__((ext_vector_type(4)));

__device__ __forceinline__ void gload_lds16(const void* g, void* l) {
    __builtin_amdgcn_global_load_lds(
        (const __attribute__((address_space(1))) unsigned int*)g,
        (__attribute__((address_space(3))) unsigned int*)l, 16, 0, 0);
}

// ---------------------------------------------------------------------------
// split w_qkv [1536][512] f32 -> wh, wl [1536][512] f16, scaled by 64
// ---------------------------------------------------------------------------
__global__ __launch_bounds__(256) void split_w_kernel(
    const float* __restrict__ w, f16* __restrict__ wh, f16* __restrict__ wl)
{
    int idx = blockIdx.x * 256 + threadIdx.x;      // OC3*CD/4 = 196608 total
    float4 v = ((const float4*)w)[idx];
    float a[4] = {v.x, v.y, v.z, v.w};
    half4v h, l;
    #pragma unroll
    for (int i = 0; i < 4; ++i) {
        float s = a[i] * 64.f;
        f16 hh = (f16)s;
        h[i] = hh;
        l[i] = (f16)(s - (float)hh);
    }
    *(half4v*)(&wh[(long)idx * 4]) = h;
    *(half4v*)(&wl[(long)idx * 4]) = l;
}

// ---------------------------------------------------------------------------
// split + transpose x [b][512 c][4096 n] f32 -> xth, xtl [b][4096 n][512 c]
// f16, scaled by 16.  64x64 tile, half8 (16B) coalesced writes.
// ---------------------------------------------------------------------------
__global__ __launch_bounds__(256) void split_x_kernel(
    const float* __restrict__ x, f16* __restrict__ xth, f16* __restrict__ xtl)
{
    __shared__ float tile[64][65];
    int b = blockIdx.z;
    int n0 = blockIdx.x * 64, c0 = blockIdx.y * 64;
    const float* xb = x + ((long)b * CD + c0) * NN + n0;
    int t = threadIdx.x;
    int tr = t >> 6, tc = t & 63;
    #pragma unroll
    for (int i = 0; i < 16; ++i)
        tile[tr + i * 4][tc] = xb[(long)(tr + i * 4) * NN + tc];
    __syncthreads();

    int nl = t >> 3, ck = (t & 7) * 8;
    long obase = ((long)b * NN + n0) * CD + c0;
    #pragma unroll
    for (int p = 0; p < 2; ++p) {
        int n = nl + p * 32;
        half8 h, l;
        #pragma unroll
        for (int j = 0; j < 8; ++j) {
            float s = tile[ck + j][n] * 16.f;
            f16 hv = (f16)s;
            h[j] = hv;
            l[j] = (f16)(s - (float)hv);
        }
        *(half8*)(&xth[obase + (long)n * CD + ck]) = h;
        *(half8*)(&xtl[obase + (long)n * CD + ck]) = l;
    }
}

// ---------------------------------------------------------------------------
// Shared 256x256 split-f16 MFMA GEMM, K=512. 3 products hh+hl+lh, fp32 accum.
// Block 512 thr = 8 waves (2Mx4N), wave tile 128x64, KT=32, 2-phase dbuf,
// LDS 128 KB.  (R12-verified: qkv 153 us MfmaUtil 46%; R8-verified fuseqv=0.)
// fuseqv != 0 (qkv pass):
//   m0 <  512 : q third -> fused softmax-over-d -> split-f16 (p*32) into
//               q region of qkv, [n][512] layout
//   m0 >= 1024: v third -> split-f16 (x16) into qkv's v region
//   else      : k third -> fp32 * base_sc
// fuseqv == 0: C = acc * base_sc * inv_sc[bz] + bias[row]  (gemm2 path)
// ---------------------------------------------------------------------------
#define AR  16384   // per-operand-array LDS bytes (256 rows x 64B)
#define BUF 65536   // per-dbuf bytes

#define STAGE(Lb, k0s)  do {                                                   \
    long kb_ = (long)(k0s) * 2;                                                \
    _Pragma("unroll")                                                          \
    for (int c_ = 0; c_ < 2; ++c_) {                                           \
        long rowoff_ = (long)(rb0 + c_ * 16) * 1024;                           \
        long ldsoff_ = (long)(rb0 + c_ * 16) * 64;                             \
        gload_lds16(gA_h + rowoff_ + kb_ + g_lane, (Lb) + 0 * AR + ldsoff_);   \
        gload_lds16(gA_l + rowoff_ + kb_ + g_lane, (Lb) + 1 * AR + ldsoff_);   \
        gload_lds16(gB_h + rowoff_ + kb_ + g_lane, (Lb) + 2 * AR + ldsoff_);   \
        gload_lds16(gB_l + rowoff_ + kb_ + g_lane, (Lb) + 3 * AR + ldsoff_);   \
    } } while (0)

__global__ __launch_bounds__(512, 2) void mfma_gemm_kernel(
    const f16* __restrict__ Ah, const f16* __restrict__ Al, long sA,
    const f16* __restrict__ Bh, const f16* __restrict__ Bl, long sB,
    float* __restrict__ Cp, long sC, int ldC,
    const float* __restrict__ bias, const float* __restrict__ inv_sc,
    float base_sc, int fuseqv)
{
    __shared__ f16 lds[2][4][256 * 32];  // 128 KB
    int bz = blockIdx.z;
    int n0 = blockIdx.x * 256, m0 = blockIdx.y * 256;
    int t = threadIdx.x;
    int lane = t & 63, wid = t >> 6;     // 8 waves
    int wy = wid >> 2, wx = wid & 3;     // 2 (M) x 4 (N)

    int cl = (lane & 3) ^ ((lane >> 3) & 3);
    long g_lane = (long)(lane >> 2) * 1024 + (long)cl * 16;

    const char* gA_h = (const char*)(Ah + bz * sA) + (long)m0 * 1024;
    const char* gA_l = (const char*)(Al + bz * sA) + (long)m0 * 1024;
    const char* gB_h = (const char*)(Bh + bz * sB) + (long)n0 * 1024;
    const char* gB_l = (const char*)(Bl + bz * sB) + (long)n0 * 1024;

    char* L0 = (char*)&lds[0][0][0];
    int rb0 = wid * 32;

    int cp = (lane >> 4) ^ (((lane & 15) >> 1) & 3);
    long offA = (long)(wy * 128 + (lane & 15)) * 64 + (long)cp * 16;
    long offB = (long)(wx * 64 + (lane & 15)) * 64 + (long)cp * 16;

    f32x4 acc[8][4];
    #pragma unroll
    for (int i = 0; i < 8; ++i)
        #pragma unroll
        for (int j = 0; j < 4; ++j)
            acc[i][j] = (f32x4){0.f, 0.f, 0.f, 0.f};

    STAGE(L0, 0);
    asm volatile("s_waitcnt vmcnt(0)" ::: "memory");
    __syncthreads();

    for (int s = 0; s < 16; ++s) {
        char* Lc = L0 + ((s & 1) ? BUF : 0);
        if (s < 15) {
            char* Ln = L0 + (((s + 1) & 1) ? BUF : 0);
            STAGE(Ln, (s + 1) * 32);
        }

        half8 ah[8], al[8];
        #pragma unroll
        for (int i = 0; i < 8; ++i) {
            ah[i] = *(const half8*)(Lc + 0 * AR + offA + i * 1024);
            al[i] = *(const half8*)(Lc + 1 * AR + offA + i * 1024);
        }
        #pragma unroll
        for (int j = 0; j < 4; ++j) {
            half8 bh = *(const half8*)(Lc + 2 * AR + offB + j * 1024);
            half8 bl = *(const half8*)(Lc + 3 * AR + offB + j * 1024);
            #pragma unroll
            for (int i = 0; i < 8; ++i) {
                acc[i][j] = __builtin_amdgcn_mfma_f32_16x16x32_f16(ah[i], bh, acc[i][j], 0, 0, 0);
                acc[i][j] = __builtin_amdgcn_mfma_f32_16x16x32_f16(ah[i], bl, acc[i][j], 0, 0, 0);
                acc[i][j] = __builtin_amdgcn_mfma_f32_16x16x32_f16(al[i], bh, acc[i][j], 0, 0, 0);
            }
        }

        asm volatile("s_waitcnt vmcnt(0)" ::: "memory");
        __syncthreads();
    }

    // C/D layout: col = lane&15, row = (lane>>4)*4 + reg
    int colb = n0 + wx * 64 + (lane & 15);
    int rowb = m0 + wy * 128 + ((lane >> 4) << 2);

    if (fuseqv && m0 < 512) {
        // q third: wave's 128 rows = heads h0, h0+1. Fused softmax over d +
        // split-f16 (p*32 = q_s*256), [n][512] layout.
        int h0 = (m0 >> 6) + wy * 2;
        f16* qh_b = (f16*)(Cp + (long)bz * sC);
        f16* ql_b = qh_b + (long)CD * NN;
        #pragma unroll
        for (int i = 0; i < 8; ++i)
            #pragma unroll
            for (int j = 0; j < 4; ++j)
                #pragma unroll
                for (int r = 0; r < 4; ++r)
                    acc[i][j][r] *= base_sc;
        #pragma unroll
        for (int j = 0; j < 4; ++j) {
            long nj = colb + j * 16;
            #pragma unroll
            for (int g = 0; g < 2; ++g) {
                float mx = -INFINITY;
                #pragma unroll
                for (int di = 0; di < 4; ++di)
                    #pragma unroll
                    for (int r = 0; r < 4; ++r)
                        mx = fmaxf(mx, acc[g * 4 + di][j][r]);
                mx = fmaxf(mx, __shfl_xor(mx, 16));
                mx = fmaxf(mx, __shfl_xor(mx, 32));
                float sum = 0.f;
                #pragma unroll
                for (int di = 0; di < 4; ++di)
                    #pragma unroll
                    for (int r = 0; r < 4; ++r) {
                        float e = expf(acc[g * 4 + di][j][r] - mx);
                        acc[g * 4 + di][j][r] = e;
                        sum += e;
                    }
                sum += __shfl_xor(sum, 16);
                sum += __shfl_xor(sum, 32);
                float rj = 32.f / sum;
                long off = nj * CD + (h0 + g) * 64 + ((lane >> 4) << 2);
                #pragma unroll
                for (int di = 0; di < 4; ++di) {
                    half4v hh, ll;
                    #pragma unroll
                    for (int r = 0; r < 4; ++r) {
                        float v = acc[g * 4 + di][j][r] * rj;
                        f16 hv = (f16)v;
                        hh[r] = hv;
                        ll[r] = (f16)(v - (float)hv);
                    }
                    *(half4v*)(qh_b + off + di * 16) = hh;
                    *(half4v*)(ql_b + off + di * 16) = ll;
                }
            }
        }
        return;
    }

    if (fuseqv && m0 >= 1024) {
        // v third: emit split-f16 (value = v_true * 16) into qkv's v region
        f16* vhp = (f16*)(Cp + (long)bz * sC + 2L * CD * NN);
        f16* vlp = vhp + (long)CD * NN;
        float vsc = base_sc * 16.f;
        #pragma unroll
        for (int i = 0; i < 8; ++i)
            #pragma unroll
            for (int j = 0; j < 4; ++j)
                #pragma unroll
                for (int r = 0; r < 4; ++r) {
                    long row = rowb + i * 16 + r - 1024;
                    float val = acc[i][j][r] * vsc;
                    f16 hv = (f16)val;
                    vhp[row * NN + colb + j * 16] = hv;
                    vlp[row * NN + colb + j * 16] = (f16)(val - (float)hv);
                }
        return;
    }

    // k third (fuseqv) or plain gemm2 epilogue
    float* outp = Cp + bz * sC;
    float mult = base_sc * (inv_sc ? inv_sc[bz] : 1.f);
    #pragma unroll
    for (int i = 0; i < 8; ++i)
        #pragma unroll
        for (int j = 0; j < 4; ++j)
            #pragma unroll
            for (int r = 0; r < 4; ++r) {
                int row = rowb + i * 16 + r;
                float bb = bias ? bias[row] : 0.f;
                outp[(long)row * ldC + colb + j * 16] = acc[i][j][r] * mult + bb;
            }
}

// ---------------------------------------------------------------------------
// k softmax row stats: per (b,hd) row of k (4096 contiguous) compute
// mx and inv = 4096/sum.  (R9-verified.)
// ---------------------------------------------------------------------------
__global__ __launch_bounds__(256) void k_rowstat_kernel(
    const float* __restrict__ qkv, float* __restrict__ statmx,
    float* __restrict__ statinv)
{
    int row = blockIdx.x;              // b*512 + hd
    int b = row >> 9;
    int hd = row & (CD - 1);
    const float* base = qkv + ((long)b * OC3 + CD + hd) * NN;
    int t = threadIdx.x;

    float v[16];
    #pragma unroll
    for (int i = 0; i < 16; ++i) v[i] = base[t + i * 256];

    __shared__ float red[256];
    float mx = -INFINITY;
    #pragma unroll
    for (int i = 0; i < 16; ++i) mx = fmaxf(mx, v[i]);
    red[t] = mx; __syncthreads();
    for (int off = 128; off > 0; off >>= 1) {
        if (t < off) red[t] = fmaxf(red[t], red[t + off]);
        __syncthreads();
    }
    mx = red[0]; __syncthreads();

    float s = 0.f;
    #pragma unroll
    for (int i = 0; i < 16; ++i) {
        v[i] = expf(v[i] - mx);
        s += v[i];
    }
    red[t] = s; __syncthreads();
    for (int off = 128; off > 0; off >>= 1) {
        if (t < off) red[t] += red[t + off];
        __syncthreads();
    }
    if (t == 0) {
        statmx[row] = mx;
        statinv[row] = 4096.f / red[0];   // k_s scaled by 2^12 for f16 split
    }
}

// ---------------------------------------------------------------------------
// context partials via split-f16 MFMA with FUSED k-softmax (R9-verified):
// per (bh, sp) block: acc[64 d][64 e] = sum over 256 n of (k_s*2^12)(v*2^4).
// k staged as raw f32 (8-chunk XOR swizzle), exp+split applied in registers;
// v from qkv's v region (pre-split f16).
// ---------------------------------------------------------------------------
__global__ __launch_bounds__(256) void ctx_mfma_kernel(
    const float* __restrict__ qkv, const float* __restrict__ statmx,
    const float* __restrict__ statinv, float* __restrict__ ctxp)
{
    __shared__ char lds[16384];          // k f32 8KB | vh 4KB | vl 4KB
    int sp = blockIdx.x;                 // K-split 0..15
    int bh = blockIdx.y;                 // 0..63
    int b = bh >> 3, h = bh & 7;
    int t = threadIdx.x, lane = t & 63, w = t >> 6;

    const char* kg = (const char*)(qkv + ((long)b * OC3 + CD + (long)h * 64) * NN);
    const char* vhg = (const char*)(qkv + ((long)b * OC3 + 2L * CD) * NN) + (long)h * 64 * (NN * 2);
    const char* vlg = vhg + (long)CD * NN * 2;

    int lr = lane & 15, hi = lane >> 4;
    float mx[4], inv[4];
    #pragma unroll
    for (int i = 0; i < 4; ++i) {
        int ridx = b * CD + h * 64 + i * 16 + lr;
        mx[i] = statmx[ridx];
        inv[i] = statinv[ridx];
    }

    int cl = (lane & 3) ^ ((lane >> 3) & 3);
    int cp16 = (hi ^ ((lr >> 1) & 3)) * 16;

    int ksrow = (lane >> 3);
    int ksc = lane & 7;

    f32x4 acc[4];
    #pragma unroll
    for (int i = 0; i < 4; ++i) acc[i] = (f32x4){0.f, 0.f, 0.f, 0.f};

    int s7 = lr & 7;

    for (int ks = 0; ks < 8; ++ks) {
        int n0 = sp * 256 + ks * 32;
        if (w < 2) {
            #pragma unroll
            for (int it2 = 0; it2 < 4; ++it2) {
                int it = w * 4 + it2;
                int r = it * 8 + ksrow;
                gload_lds16(kg + (long)r * (NN * 4) + (long)n0 * 4 + ((ksc ^ (r & 7)) << 4),
                            lds + it * 1024 + lane * 16);
            }
        } else {
            const char* gv = (w == 2) ? vhg : vlg;
            char* lv = lds + 8192 + (w - 2) * 4096;
            #pragma unroll
            for (int c2 = 0; c2 < 4; ++c2)
                gload_lds16(gv + (long)(c2 * 16 + (lane >> 2)) * (NN * 2) + (long)n0 * 2 + (long)cl * 16,
                            lv + c2 * 1024 + lane * 16);
        }
        asm volatile("s_waitcnt vmcnt(0)" ::: "memory");
        __syncthreads();

        half8 ah[4], al[4];
        #pragma unroll
        for (int i = 0; i < 4; ++i) {
            int row = i * 16 + lr;
            const char* rb = lds + row * 128;
            f32x4 a0 = *(const f32x4*)(rb + (((2 * hi) ^ s7) << 4));
            f32x4 a1 = *(const f32x4*)(rb + (((2 * hi + 1) ^ s7) << 4));
            #pragma unroll
            for (int j = 0; j < 8; ++j) {
                float kv = (j < 4) ? a0[j] : a1[j - 4];
                float e = expf(kv - mx[i]) * inv[i];
                f16 hv = (f16)e;
                ah[i][j] = hv;
                al[i][j] = (f16)(e - (float)hv);
            }
        }
        half8 bhf = *(const half8*)(lds + 8192 + (w * 16 + lr) * 64 + cp16);
        half8 blf = *(const half8*)(lds + 12288 + (w * 16 + lr) * 64 + cp16);
        #pragma unroll
        for (int i = 0; i < 4; ++i) {
            acc[i] = __builtin_amdgcn_mfma_f32_16x16x32_f16(ah[i], bhf, acc[i], 0, 0, 0);
            acc[i] = __builtin_amdgcn_mfma_f32_16x16x32_f16(ah[i], blf, acc[i], 0, 0, 0);
            acc[i] = __builtin_amdgcn_mfma_f32_16x16x32_f16(al[i], bhf, acc[i], 0, 0, 0);
        }
        __syncthreads();
    }

    float* op = ctxp + ((long)bh * NSPLIT + sp) * 4096;
    #pragma unroll
    for (int i = 0; i < 4; ++i)
        #pragma unroll
        for (int r = 0; r < 4; ++r)
            op[(i * 16 + hi * 4 + r) * 64 + w * 16 + lr] = acc[i][r];
}

// ---------------------------------------------------------------------------
// reduce partials in fp64; undo scales: /(2^12 * 2^4) and /N  => * 2^-28
// ---------------------------------------------------------------------------
__global__ __launch_bounds__(256) void context_reduce_kernel(
    const float* __restrict__ ctxp, float* __restrict__ ctx)
{
    int idx = blockIdx.x * 256 + threadIdx.x;
    int bh = idx >> 12;
    int de = idx & 4095;
    double s = 0.0;
    #pragma unroll
    for (int sp = 0; sp < NSPLIT; ++sp)
        s += (double)ctxp[((long)bh * NSPLIT + sp) * 4096 + de];
    ctx[idx] = (float)(s * (1.0 / 268435456.0));
}

// ---------------------------------------------------------------------------
// fold w_out into per-batch M (row-major [c][hd]) — LDS-tiled (R12 version):
// block = (c-tile 128, bh); ctx[b,h] (64x64) staged once in LDS (65-pad).
// ---------------------------------------------------------------------------
__global__ __launch_bounds__(256) void fold_wout_kernel(
    const float* __restrict__ w_out, const float* __restrict__ ctx,
    float* __restrict__ Mf)
{
    __shared__ float cl[64][65];
    int ct = blockIdx.x;               // c-tile 0..3
    int bh = blockIdx.y;               // b*8+h
    int b = bh >> 3, h = bh & 7;
    int t = threadIdx.x;
    const float* cp = ctx + (long)bh * 4096;
    #pragma unroll
    for (int i = 0; i < 16; ++i) {
        int o = t + i * 256;
        cl[o >> 6][o & 63] = cp[o];
    }
    __syncthreads();

    int d = t & 63, tc = t >> 6;       // 4 c-subgroups of 32
    #pragma unroll 4
    for (int ci = 0; ci < 32; ++ci) {
        int c = ct * 128 + tc * 32 + ci;
        const float* wr = w_out + (long)c * CD + h * DD;
        float s = 0.f;
        #pragma unroll
        for (int e = 0; e < 64; ++e) s += wr[e] * cl[d][e];
        Mf[((long)b * CD + c) * CD + h * DD + d] = s;
    }
}

// ---------------------------------------------------------------------------
// per-batch max|M| two-stage: 32 partial blocks per batch, then final.
// ---------------------------------------------------------------------------
__global__ __launch_bounds__(256) void max_m_part_kernel(
    const float* __restrict__ Mf, float* __restrict__ part)
{
    int blk = blockIdx.x;              // 256 blocks: b = blk>>5, sub = blk&31
    int b = blk >> 5, sub = blk & 31;
    const float4* p = (const float4*)(Mf + (long)b * CD * CD) + (long)sub * 2048;
    float mx = 0.f;
    for (int i = threadIdx.x; i < 2048; i += 256) {
        float4 v = p[i];
        mx = fmaxf(mx, fmaxf(fmaxf(fabsf(v.x), fabsf(v.y)),
                             fmaxf(fabsf(v.z), fabsf(v.w))));
    }
    __shared__ float red[256];
    red[threadIdx.x] = mx; __syncthreads();
    for (int off = 128; off > 0; off >>= 1) {
        if (threadIdx.x < off) red[threadIdx.x] = fmaxf(red[threadIdx.x], red[threadIdx.x + off]);
        __syncthreads();
    }
    if (threadIdx.x == 0) part[blk] = red[0];
}

__global__ __launch_bounds__(64) void max_m_final_kernel(
    const float* __restrict__ part, float* __restrict__ scl)
{
    int b = threadIdx.x;
    if (b < 8) {
        float m = 0.f;
        #pragma unroll
        for (int i = 0; i < 32; ++i) m = fmaxf(m, part[b * 32 + i]);
        int e = (m > 1e-30f) ? ilogbf(m) : 0;
        scl[b] = ldexpf(1.f, 10 - e);
        scl[8 + b] = ldexpf(1.f, e - 10);
    }
}

// ---------------------------------------------------------------------------
// split M fp32 -> mh/ml f16 with per-batch scale
// ---------------------------------------------------------------------------
__global__ __launch_bounds__(256) void split_m_kernel(
    const float* __restrict__ Mf, const float* __restrict__ scl,
    f16* __restrict__ mh, f16* __restrict__ ml)
{
    int idx = blockIdx.x * 256 + threadIdx.x;   // BB*CD*CD/4 float4s
    float s = scl[idx >> 16];                   // 65536 float4s per batch
    float4 v = ((const float4*)Mf)[idx];
    float a[4] = {v.x, v.y, v.z, v.w};
    half4v h, l;
    #pragma unroll
    for (int i = 0; i < 4; ++i) {
        float tval = a[i] * s;
        f16 hv = (f16)tval;
        h[i] = hv;
        l[i] = (f16)(tval - (float)hv);
    }
    *(half4v*)(&mh[(long)idx * 4]) = h;
    *(half4v*)(&ml[(long)idx * 4]) = l;
}

// ---------------------------------------------------------------------------
// channel LayerNorm over c=512 (stride NN), fp64 stats, values reg-cached.
// ---------------------------------------------------------------------------
__global__ __launch_bounds__(256) void layernorm_kernel(
    const float* __restrict__ qkv, const float* __restrict__ g,
    float* __restrict__ out)
{
    int t = threadIdx.x;
    int tn = t & 31, cy = t >> 5;              // col-in-block, c-group
    long col = (long)blockIdx.x * 32 + tn;     // 0..32767
    int n = (int)(col & (NN - 1));
    int b = (int)(col >> 12);
    const float* base = qkv + (long)b * OC3 * NN + (long)CD * NN + n;

    float v[64];
    double s = 0.0, ss = 0.0;
    #pragma unroll
    for (int i = 0; i < 64; ++i) {
        v[i] = base[(long)(cy * 64 + i) * NN];
        s += (double)v[i];
        ss += (double)v[i] * (double)v[i];
    }

    __shared__ double rs[8][32], rss[8][32];
    rs[cy][tn] = s; rss[cy][tn] = ss;
    __syncthreads();
    __shared__ float mb[32], ib[32];
    if (cy == 0) {
        double S = 0.0, SS = 0.0;
        #pragma unroll
        for (int j = 0; j < 8; ++j) { S += rs[j][tn]; SS += rss[j][tn]; }
        double mean = S * (1.0 / CD);
        double var = SS * (1.0 / CD) - mean * mean;
        mb[tn] = (float)mean;
        ib[tn] = (float)(1.0 / sqrt(var + 1e-5));
    }
    __syncthreads();
    float m = mb[tn], iv = ib[tn];

    float* oc = out + (long)b * CD * NN + n;
    #pragma unroll
    for (int i = 0; i < 64; ++i)
        oc[(long)(cy * 64 + i) * NN] = (v[i] - m) * iv * g[cy * 64 + i];
}

// ---------------------------------------------------------------------------
extern "C" void kernel_launch(void* const* d_in, const int* in_sizes, int n_in,
                              void* d_out, int out_size, void* d_ws, size_t ws_size,
                              hipStream_t stream)
{
    const float* x     = (const float*)d_in[0];
    const float* w_qkv = (const float*)d_in[1];
    const float* w_out = (const float*)d_in[2];
    const float* b_out = (const float*)d_in[3];
    const float* g     = (const float*)d_in[4];
    float* out = (float*)d_out;

    float* ws   = (float*)d_ws;
    float* qkv  = ws;                                      // 50,331,648 f
    float* ctxp = qkv + (long)BB * OC3 * NN;               //  4,194,304 f (reused for Mf)
    float* ctx  = ctxp + (long)BB * HH * NSPLIT * DD * DD; //    262,144 f
    f16*   mh   = (f16*)(ctx + (long)BB * HH * DD * DD);   //  2,097,152 h
    f16*   ml   = mh + (long)BB * CD * CD;                 //  2,097,152 h
    f16*   wh   = (f16*)(ml + (long)BB * CD * CD);         //    786,432 h
    f16*   wl   = wh + (long)OC3 * CD;                     //    786,432 h
    float* scl  = (float*)(wl + (long)OC3 * CD);           //         16 f
    float* part = scl + 16;                                //        256 f
    float* statmx = part + 256;                            //      4,096 f
    float* statinv = statmx + BB * CD;                     //      4,096 f
    float* Mf   = ctxp;                                    // ctxp dead by then

    // d_out as scratch: xth/xtl (consumed by qkv GEMM) -> final out
    f16* xth = (f16*)d_out;
    f16* xtl = xth + (long)BB * NN * CD;

    // 0) operand splits
    split_w_kernel<<<(OC3 * CD / 4) / 256, 256, 0, stream>>>(w_qkv, wh, wl);
    split_x_kernel<<<dim3(NN / 64, CD / 64, BB), 256, 0, stream>>>(x, xth, xtl);

    // 1) qkv = w_qkv @ x via split-f16 MFMA, fused epilogues (q softmax+split,
    //    k fp32, v split). 256x256 tiles, 512 threads.
    mfma_gemm_kernel<<<dim3(NN / 256, OC3 / 256, BB), 512, 0, stream>>>(
        wh, wl, 0L, xth, xtl, (long)NN * CD,
        qkv, (long)OC3 * NN, NN, nullptr, nullptr, 1.0f / 1024.0f, 1);

    // 2) k softmax row stats only (mx, 4096/sum) — R9 fused k-path
    k_rowstat_kernel<<<BB * CD, 256, 0, stream>>>(qkv, statmx, statinv);

    // 3) context partials via MFMA with fused exp+split on k + fp64 reduce
    ctx_mfma_kernel<<<dim3(NSPLIT, BB * HH), 256, 0, stream>>>(
        qkv, statmx, statinv, ctxp);
    context_reduce_kernel<<<(BB * HH * DD * DD) / 256, 256, 0, stream>>>(ctxp, ctx);

    // 4) M = fold(w_out, ctx) -> Mf (ws); pow2 scale; f16 split
    fold_wout_kernel<<<dim3(4, BB * HH), 256, 0, stream>>>(w_out, ctx, Mf);
    max_m_part_kernel<<<256, 256, 0, stream>>>(Mf, part);
    max_m_final_kernel<<<1, 64, 0, stream>>>(part, scl);
    split_m_kernel<<<(BB * CD * CD / 4) / 256, 256, 0, stream>>>(Mf, scl, mh, ml);

    // 5) y = M_b @ q_s + b_out via split-f16 MFMA at 256x256 (R8-vs-R10
    //    isolated: 256-sq gemm2 is ~15 us faster than 128-sq) -> dead k
    //    region of qkv.  B operand = qh/ql in q region ([n][512] layout).
    mfma_gemm_kernel<<<dim3(NN / 256, CD / 256, BB), 512, 0, stream>>>(
        mh, ml, (long)CD * CD,
        (const f16*)qkv, (const f16*)qkv + (long)CD * NN, (long)OC3 * NN * 2,
        qkv + (long)CD * NN, (long)OC3 * NN, NN, b_out, scl + 8,
        1.0f / 256.0f, 0);

    // 6) channel LayerNorm -> d_out
    layernorm_kernel<<<(BB * NN) / 32, 256, 0, stream>>>(qkv, g, out);
}